// Round 1
// baseline (622.503 us; speedup 1.0000x reference)
//
#include <hip/hip_runtime.h>
#include <stdint.h>

// Round 0: correctness-first full MHA pipeline, bf16 MFMA everywhere.
// Structure: cvt_x -> wtrans(x4) -> qkv_gemm(z=3) -> rope -> vtrans -> flash attn -> proj_gemm.
// Deliberately NO global_load_lds yet (isolate compile/correctness risk); that is the R1 change.

typedef unsigned short u16;
typedef __attribute__((ext_vector_type(8))) short bf16x8;   // 8 x bf16 (4 VGPRs)
typedef __attribute__((ext_vector_type(4))) float f32x4;

#define SEQ 2048
#define DM 2048
#define NH 16
#define HD 128
#define SM_SCALE 0.08838834764831845f   // 1/sqrt(128)

__device__ __forceinline__ u16 f2bf(float f) {
  union { float f; uint32_t u; } v; v.f = f;
  uint32_t u = v.u + 0x7fffu + ((v.u >> 16) & 1u);   // RNE
  return (u16)(u >> 16);
}
__device__ __forceinline__ float bf2f(u16 h) {
  union { uint32_t u; float f; } v; v.u = ((uint32_t)h) << 16; return v.f;
}

// ---------------- elementwise fp32 -> bf16 of x ----------------
__global__ __launch_bounds__(256) void cvt_x(const float* __restrict__ x, u16* __restrict__ xb) {
  int i = blockIdx.x * 256 + threadIdx.x;          // over 2,097,152 float4s
  float4 v = ((const float4*)x)[i];
  uint2 r;
  r.x = (uint32_t)f2bf(v.x) | ((uint32_t)f2bf(v.y) << 16);
  r.y = (uint32_t)f2bf(v.z) | ((uint32_t)f2bf(v.w) << 16);
  ((uint2*)xb)[i] = r;
}

// ---------------- W (K,N) fp32 -> Wt (N,K) bf16, tiled transpose ----------------
__global__ __launch_bounds__(256) void wtrans(const float* __restrict__ w0, const float* __restrict__ w1,
                                              const float* __restrict__ w2, const float* __restrict__ w3,
                                              u16* __restrict__ dst) {
  const float* W = blockIdx.z == 0 ? w0 : blockIdx.z == 1 ? w1 : blockIdx.z == 2 ? w2 : w3;
  u16* D = dst + (size_t)blockIdx.z * DM * DM;
  int k0 = blockIdx.x * 32, n0 = blockIdx.y * 32;
  __shared__ u16 t[32][33];
  int tx = threadIdx.x, ty = threadIdx.y;   // (32,8)
#pragma unroll
  for (int i = 0; i < 32; i += 8)
    t[ty + i][tx] = f2bf(W[(size_t)(k0 + ty + i) * DM + n0 + tx]);
  __syncthreads();
#pragma unroll
  for (int i = 0; i < 32; i += 8)
    D[(size_t)(n0 + ty + i) * DM + k0 + tx] = t[tx][ty + i];
}

// ---------------- 128x128x(BK=64) bf16 MFMA GEMM core ----------------
// A: (M,K) row-major bf16. Bt: (N,K) row-major bf16. 4 waves, each 64x64 (4x4 tiles of 16x16x32).
__device__ __forceinline__ void gemm_core(const u16* __restrict__ A, const u16* __restrict__ Bt,
                                          int m0, int n0, u16* As, u16* Bs, f32x4 acc[4][4]) {
  int tid = threadIdx.x, lane = tid & 63;
  int l15 = lane & 15, quad = lane >> 4;
  int wave = tid >> 6;
  int wm = (wave >> 1) * 64, wn = (wave & 1) * 64;
  for (int k0 = 0; k0 < DM; k0 += 64) {
#pragma unroll
    for (int i = 0; i < 4; ++i) {
      int chunk = tid + i * 256;             // 1024 chunks of 8 elems per 128x64 tile
      int row = chunk >> 3, c8 = (chunk & 7) << 3;
      *(uint4*)&As[row * 72 + c8] = *(const uint4*)&A[(size_t)(m0 + row) * DM + k0 + c8];
      *(uint4*)&Bs[row * 72 + c8] = *(const uint4*)&Bt[(size_t)(n0 + row) * DM + k0 + c8];
    }
    __syncthreads();
#pragma unroll
    for (int kk = 0; kk < 2; ++kk) {
      bf16x8 af[4], bfr[4];
#pragma unroll
      for (int mt = 0; mt < 4; ++mt)
        af[mt] = *(const bf16x8*)&As[(wm + mt * 16 + l15) * 72 + kk * 32 + quad * 8];
#pragma unroll
      for (int nt = 0; nt < 4; ++nt)
        bfr[nt] = *(const bf16x8*)&Bs[(wn + nt * 16 + l15) * 72 + kk * 32 + quad * 8];
#pragma unroll
      for (int mt = 0; mt < 4; ++mt)
#pragma unroll
        for (int nt = 0; nt < 4; ++nt)
          acc[mt][nt] = __builtin_amdgcn_mfma_f32_16x16x32_bf16(af[mt], bfr[nt], acc[mt][nt], 0, 0, 0);
    }
    __syncthreads();
  }
}

__global__ __launch_bounds__(256) void qkv_gemm(const u16* __restrict__ X, const u16* __restrict__ Wt,
                                                u16* __restrict__ Qo, u16* __restrict__ Ko,
                                                u16* __restrict__ Vo) {
  __shared__ u16 As[128 * 72];
  __shared__ u16 Bs[128 * 72];
  const u16* Bt = Wt + (size_t)blockIdx.z * DM * DM;
  u16* C = blockIdx.z == 0 ? Qo : blockIdx.z == 1 ? Ko : Vo;
  int n0 = blockIdx.x * 128, m0 = blockIdx.y * 128;
  f32x4 acc[4][4] = {};
  gemm_core(X, Bt, m0, n0, As, Bs, acc);
  int lane = threadIdx.x & 63, wave = threadIdx.x >> 6;
  int l15 = lane & 15, quad = lane >> 4;
  int wm = (wave >> 1) * 64, wn = (wave & 1) * 64;
#pragma unroll
  for (int mt = 0; mt < 4; ++mt)
#pragma unroll
    for (int nt = 0; nt < 4; ++nt)
#pragma unroll
      for (int r = 0; r < 4; ++r)
        C[(size_t)(m0 + wm + mt * 16 + quad * 4 + r) * DM + n0 + wn + nt * 16 + l15] = f2bf(acc[mt][nt][r]);
}

__global__ __launch_bounds__(256) void proj_gemm(const u16* __restrict__ A, const u16* __restrict__ Wt,
                                                 float* __restrict__ C) {
  __shared__ u16 As[128 * 72];
  __shared__ u16 Bs[128 * 72];
  int n0 = blockIdx.x * 128, m0 = blockIdx.y * 128;
  f32x4 acc[4][4] = {};
  gemm_core(A, Wt, m0, n0, As, Bs, acc);
  int lane = threadIdx.x & 63, wave = threadIdx.x >> 6;
  int l15 = lane & 15, quad = lane >> 4;
  int wm = (wave >> 1) * 64, wn = (wave & 1) * 64;
#pragma unroll
  for (int mt = 0; mt < 4; ++mt)
#pragma unroll
    for (int nt = 0; nt < 4; ++nt)
#pragma unroll
      for (int r = 0; r < 4; ++r)
        C[(size_t)(m0 + wm + mt * 16 + quad * 4 + r) * DM + n0 + wn + nt * 16 + l15] = acc[mt][nt][r];
}

// ---------------- RoPE in-place on Q (y=0) and K (y=1) ----------------
__global__ __launch_bounds__(256) void rope_k(u16* __restrict__ Q, u16* __restrict__ K,
                                              const int* __restrict__ pos) {
  uint32_t idx = blockIdx.x * 256 + threadIdx.x;  // over 2*2048*16*64 = 4,194,304
  int i = idx & 63;
  int h = (idx >> 6) & 15;
  int s = (idx >> 10) & 2047;
  int b = idx >> 21;
  u16* P = (blockIdx.y == 0) ? Q : K;
  int p = pos[b * SEQ + s];
  float inv = powf(10000.0f, -(float)i * (1.0f / 64.0f));
  float ang = (float)p * inv;
  float sn, cs;
  sincosf(ang, &sn, &cs);
  size_t base = ((size_t)(b * SEQ + s)) * DM + h * HD;
  float x1 = bf2f(P[base + i]), x2 = bf2f(P[base + 64 + i]);
  P[base + i] = f2bf(x1 * cs - x2 * sn);
  P[base + 64 + i] = f2bf(x2 * cs + x1 * sn);
}

// ---------------- V (b,s,h*128+d) -> Vt (b,h,d,s) ----------------
__global__ __launch_bounds__(256) void vtrans(const u16* __restrict__ V, u16* __restrict__ Vt) {
  int b = blockIdx.z >> 4, h = blockIdx.z & 15;
  int s0 = blockIdx.x * 32, d0 = blockIdx.y * 32;
  __shared__ u16 t[32][33];
  int tx = threadIdx.x, ty = threadIdx.y;   // (32,8)
#pragma unroll
  for (int i = 0; i < 32; i += 8)
    t[ty + i][tx] = V[(size_t)(b * SEQ + s0 + ty + i) * DM + h * HD + d0 + tx];
  __syncthreads();
#pragma unroll
  for (int i = 0; i < 32; i += 8)
    Vt[((size_t)(b * NH + h) * HD + d0 + ty + i) * SEQ + s0 + tx] = t[tx][ty + i];
}

// ---------------- Flash attention: Q-tile 128, K-tile 64, 4 waves x 32 q-rows ----------------
__global__ __launch_bounds__(256) void attn_k(const u16* __restrict__ Q, const u16* __restrict__ K,
                                              const u16* __restrict__ Vt, const int* __restrict__ pos,
                                              u16* __restrict__ AO) {
  __shared__ u16 Ks[64 * 136];   // (j, d) padded
  __shared__ u16 Vs[128 * 72];   // (d, j) padded  (V^T tile)
  __shared__ u16 Ps[128 * 72];   // (q, j) padded
  __shared__ int pk[64];
  int qt = blockIdx.x, bh = blockIdx.y;
  int b = bh >> 4, h = bh & 15;
  int q0 = qt * 128;
  int tid = threadIdx.x, lane = tid & 63, wave = tid >> 6;
  int l15 = lane & 15, quad = lane >> 4;
  const int* posb = pos + b * SEQ;

  // Q fragments resident in registers (A-layout): rows wave*32 + mt*16 + l15
  bf16x8 qf[2][4];
#pragma unroll
  for (int mt = 0; mt < 2; ++mt)
#pragma unroll
    for (int kk = 0; kk < 4; ++kk)
      qf[mt][kk] = *(const bf16x8*)&Q[(size_t)(b * SEQ + q0 + wave * 32 + mt * 16 + l15) * DM
                                      + h * HD + kk * 32 + quad * 8];
  int pq[2][4];
#pragma unroll
  for (int mt = 0; mt < 2; ++mt)
#pragma unroll
    for (int r = 0; r < 4; ++r)
      pq[mt][r] = posb[q0 + wave * 32 + mt * 16 + quad * 4 + r];
  int pqmax = posb[q0 + 127];

  float m_i[2][4], l_i[2][4];
  f32x4 oacc[2][8] = {};
#pragma unroll
  for (int mt = 0; mt < 2; ++mt)
#pragma unroll
    for (int r = 0; r < 4; ++r) { m_i[mt][r] = -1.0e30f; l_i[mt][r] = 0.0f; }

  for (int j0 = 0; j0 < SEQ; j0 += 64) {
    if (posb[j0] > pqmax) break;   // sorted positions: every later tile fully masked
    // stage K tile (64x128) and Vt tile (128x64)
#pragma unroll
    for (int i = 0; i < 4; ++i) {
      int chunk = tid + i * 256;
      { int row = chunk >> 4, c8 = (chunk & 15) << 3;
        *(uint4*)&Ks[row * 136 + c8] = *(const uint4*)&K[(size_t)(b * SEQ + j0 + row) * DM + h * HD + c8]; }
      { int row = chunk >> 3, c8 = (chunk & 7) << 3;
        *(uint4*)&Vs[row * 72 + c8] = *(const uint4*)&Vt[((size_t)(b * NH + h) * HD + row) * SEQ + j0 + c8]; }
    }
    if (tid < 64) pk[tid] = posb[j0 + tid];
    __syncthreads();

    // S = Q K^T  (2 m-tiles x 4 n-tiles)
    f32x4 sacc[2][4] = {};
#pragma unroll
    for (int kk = 0; kk < 4; ++kk) {
      bf16x8 bk[4];
#pragma unroll
      for (int nt = 0; nt < 4; ++nt)
        bk[nt] = *(const bf16x8*)&Ks[(nt * 16 + l15) * 136 + kk * 32 + quad * 8];
#pragma unroll
      for (int mt = 0; mt < 2; ++mt)
#pragma unroll
        for (int nt = 0; nt < 4; ++nt)
          sacc[mt][nt] = __builtin_amdgcn_mfma_f32_16x16x32_bf16(qf[mt][kk], bk[nt], sacc[mt][nt], 0, 0, 0);
    }

    // mask + online softmax (C-layout: row = quad*4+r, col = nt*16+l15)
#pragma unroll
    for (int mt = 0; mt < 2; ++mt) {
#pragma unroll
      for (int r = 0; r < 4; ++r) {
        float rowm = -3.0e38f;
#pragma unroll
        for (int nt = 0; nt < 4; ++nt) {
          float s = sacc[mt][nt][r] * SM_SCALE;
          s = (pq[mt][r] >= pk[nt * 16 + l15]) ? s : -1.0e30f;
          sacc[mt][nt][r] = s;
          rowm = fmaxf(rowm, s);
        }
#pragma unroll
        for (int off = 1; off < 16; off <<= 1) rowm = fmaxf(rowm, __shfl_xor(rowm, off));
        float mn = fmaxf(m_i[mt][r], rowm);
        float al = __expf(m_i[mt][r] - mn);
        m_i[mt][r] = mn;
        float rsl = 0.0f;
#pragma unroll
        for (int nt = 0; nt < 4; ++nt) {
          float p = __expf(sacc[mt][nt][r] - mn);
          rsl += p;
          Ps[(wave * 32 + mt * 16 + quad * 4 + r) * 72 + nt * 16 + l15] = f2bf(p);
        }
#pragma unroll
        for (int off = 1; off < 16; off <<= 1) rsl += __shfl_xor(rsl, off);
        l_i[mt][r] = l_i[mt][r] * al + rsl;
#pragma unroll
        for (int nd = 0; nd < 8; ++nd) oacc[mt][nd][r] *= al;
      }
    }
    __syncthreads();   // Ps visibility (and keeps Ks/Vs stable until all waves pass)

    // O += P @ V   (A-frags from Ps, B-frags from Vs = V^T tile)
#pragma unroll
    for (int kk = 0; kk < 2; ++kk) {
      bf16x8 ap[2], bv[8];
#pragma unroll
      for (int mt = 0; mt < 2; ++mt)
        ap[mt] = *(const bf16x8*)&Ps[(wave * 32 + mt * 16 + l15) * 72 + kk * 32 + quad * 8];
#pragma unroll
      for (int nd = 0; nd < 8; ++nd)
        bv[nd] = *(const bf16x8*)&Vs[(nd * 16 + l15) * 72 + kk * 32 + quad * 8];
#pragma unroll
      for (int mt = 0; mt < 2; ++mt)
#pragma unroll
        for (int nd = 0; nd < 8; ++nd)
          oacc[mt][nd] = __builtin_amdgcn_mfma_f32_16x16x32_bf16(ap[mt], bv[nd], oacc[mt][nd], 0, 0, 0);
    }
    __syncthreads();   // before next staging overwrites Ks/Vs/Ps
  }

  // epilogue: O /= l, write bf16 (b, s, h*128+d)
#pragma unroll
  for (int mt = 0; mt < 2; ++mt)
#pragma unroll
    for (int r = 0; r < 4; ++r) {
      float inv = 1.0f / l_i[mt][r];
#pragma unroll
      for (int nd = 0; nd < 8; ++nd)
        AO[(size_t)(b * SEQ + q0 + wave * 32 + mt * 16 + quad * 4 + r) * DM + h * HD + nd * 16 + l15]
            = f2bf(oacc[mt][nd][r] * inv);
    }
}

extern "C" void kernel_launch(void* const* d_in, const int* in_sizes, int n_in,
                              void* d_out, int out_size, void* d_ws, size_t ws_size,
                              hipStream_t stream) {
  const float* x  = (const float*)d_in[0];
  const float* Wq = (const float*)d_in[1];
  const float* Wk = (const float*)d_in[2];
  const float* Wv = (const float*)d_in[3];
  const float* Wo = (const float*)d_in[4];
  const int*  pos = (const int*)d_in[5];
  float* out = (float*)d_out;

  u16* ws  = (u16*)d_ws;
  u16* xb  = ws;                                   // 4096*2048
  u16* wt  = xb  + (size_t)4096 * 2048;            // 4 * 2048*2048 (q,k,v,o) transposed (N,K)
  u16* qb  = wt  + (size_t)4 * 2048 * 2048;
  u16* kb  = qb  + (size_t)4096 * 2048;
  u16* vb  = kb  + (size_t)4096 * 2048;
  u16* vtb = vb  + (size_t)4096 * 2048;
  u16* aob = vtb + (size_t)4096 * 2048;            // total 128 MiB

  cvt_x<<<8192, 256, 0, stream>>>(x, xb);
  wtrans<<<dim3(64, 64, 4), dim3(32, 8), 0, stream>>>(Wq, Wk, Wv, Wo, wt);
  qkv_gemm<<<dim3(16, 32, 3), 256, 0, stream>>>(xb, wt, qb, kb, vb);
  rope_k<<<dim3(16384, 2), 256, 0, stream>>>(qb, kb, pos);
  vtrans<<<dim3(64, 4, 32), dim3(32, 8), 0, stream>>>(vb, vtb);
  attn_k<<<dim3(16, 32), 256, 0, stream>>>(qb, kb, vtb, pos, aob);
  proj_gemm<<<dim3(16, 32), 256, 0, stream>>>(aob, wt + (size_t)3 * 2048 * 2048, out);
}

// Round 2
// 486.429 us; speedup vs baseline: 1.2797x; 1.2797x over previous
//
#include <hip/hip_runtime.h>
#include <stdint.h>

// R2: (1) attn: S^T=K·Q^T layout -> 2-shuffle softmax + in-register P^T frags (no Ps LDS,
//     no 3rd barrier), Q-tile 64, LDS 33KB -> 4 blocks/CU, 1024 blocks.
//     (2) m97 recipe for GEMMs + attn staging: global_load_lds width=16, XOR-swizzled
//     unpadded LDS (2-way conflicts = free).
//     (3) vtrans fused into V-GEMM epilogue (transposed packed store).

typedef unsigned short u16;
typedef unsigned int u32;
typedef __attribute__((ext_vector_type(8))) short bf16x8;
typedef __attribute__((ext_vector_type(4))) float f32x4;

#define SEQ 2048
#define DM 2048
#define NH 16
#define HD 128
#define SM_SCALE 0.08838834764831845f   // 1/sqrt(128)

__device__ __forceinline__ u16 f2bf(float f) {
  union { float f; uint32_t u; } v; v.f = f;
  uint32_t u = v.u + 0x7fffu + ((v.u >> 16) & 1u);   // RNE
  return (u16)(u >> 16);
}
__device__ __forceinline__ float bf2f(u16 h) {
  union { uint32_t u; float f; } v; v.u = ((uint32_t)h) << 16; return v.f;
}
__device__ __forceinline__ u32 pack2(float a, float b) {
  return (u32)f2bf(a) | ((u32)f2bf(b) << 16);
}

// async global->LDS, 16B per lane. LDS dest is wave-uniform base + lane*16.
__device__ __forceinline__ void gl2lds16(const void* g, void* l) {
  __builtin_amdgcn_global_load_lds(
      (const __attribute__((address_space(1))) uint32_t*)g,
      (__attribute__((address_space(3))) uint32_t*)l, 16, 0, 0);
}

// ---------------- elementwise fp32 -> bf16 of x ----------------
__global__ __launch_bounds__(256) void cvt_x(const float* __restrict__ x, u16* __restrict__ xb) {
  int i = blockIdx.x * 256 + threadIdx.x;
  float4 v = ((const float4*)x)[i];
  uint2 r;
  r.x = pack2(v.x, v.y);
  r.y = pack2(v.z, v.w);
  ((uint2*)xb)[i] = r;
}

// ---------------- W (K,N) fp32 -> Wt (N,K) bf16, tiled transpose ----------------
__global__ __launch_bounds__(256) void wtrans(const float* __restrict__ w0, const float* __restrict__ w1,
                                              const float* __restrict__ w2, const float* __restrict__ w3,
                                              u16* __restrict__ dst) {
  const float* W = blockIdx.z == 0 ? w0 : blockIdx.z == 1 ? w1 : blockIdx.z == 2 ? w2 : w3;
  u16* D = dst + (size_t)blockIdx.z * DM * DM;
  int k0 = blockIdx.x * 32, n0 = blockIdx.y * 32;
  __shared__ u16 t[32][33];
  int tx = threadIdx.x, ty = threadIdx.y;   // (32,8)
#pragma unroll
  for (int i = 0; i < 32; i += 8)
    t[ty + i][tx] = f2bf(W[(size_t)(k0 + ty + i) * DM + n0 + tx]);
  __syncthreads();
#pragma unroll
  for (int i = 0; i < 32; i += 8)
    D[(size_t)(n0 + ty + i) * DM + k0 + tx] = t[tx][ty + i];
}

// ---------------- 128x128 (BK=64) bf16 MFMA GEMM core, global_load_lds staging ----------------
// LDS tile layout: 16B chunk (row, c) stored at slot row*8 + (c ^ (row&7)); unpadded.
__device__ __forceinline__ void gemm_core(const u16* __restrict__ A, const u16* __restrict__ Bt,
                                          int m0, int n0, u16* As, u16* Bs, f32x4 acc[4][4]) {
  int tid = threadIdx.x, lane = tid & 63;
  int l15 = lane & 15, quad = lane >> 4;
  int wave = tid >> 6;
  int wm = (wave >> 1) * 64, wn = (wave & 1) * 64;
  for (int k0 = 0; k0 < DM; k0 += 64) {
#pragma unroll
    for (int i = 0; i < 4; ++i) {
      int s = i * 256 + tid;
      int row = s >> 3, c = (s & 7) ^ (row & 7);
      gl2lds16(&A[(size_t)(m0 + row) * DM + k0 + c * 8], &As[(s & ~63) * 8]);
      gl2lds16(&Bt[(size_t)(n0 + row) * DM + k0 + c * 8], &Bs[(s & ~63) * 8]);
    }
    __syncthreads();
#pragma unroll
    for (int kk = 0; kk < 2; ++kk) {
      bf16x8 af[4], bfr[4];
#pragma unroll
      for (int mt = 0; mt < 4; ++mt) {
        int row = wm + mt * 16 + l15;
        int c = (kk * 4 + quad) ^ (row & 7);
        af[mt] = *(const bf16x8*)&As[row * 64 + c * 8];
      }
#pragma unroll
      for (int nt = 0; nt < 4; ++nt) {
        int row = wn + nt * 16 + l15;
        int c = (kk * 4 + quad) ^ (row & 7);
        bfr[nt] = *(const bf16x8*)&Bs[row * 64 + c * 8];
      }
#pragma unroll
      for (int mt = 0; mt < 4; ++mt)
#pragma unroll
        for (int nt = 0; nt < 4; ++nt)
          acc[mt][nt] = __builtin_amdgcn_mfma_f32_16x16x32_bf16(af[mt], bfr[nt], acc[mt][nt], 0, 0, 0);
    }
    __syncthreads();
  }
}

// z=0 -> Q, z=1 -> K (row-major bf16), z=2 -> V stored TRANSPOSED into Vt (b,h,d,s)
__global__ __launch_bounds__(256) void qkv_gemm(const u16* __restrict__ X, const u16* __restrict__ Wt,
                                                u16* __restrict__ Qo, u16* __restrict__ Ko,
                                                u16* __restrict__ Vto) {
  __shared__ u16 As[128 * 64];
  __shared__ u16 Bs[128 * 64];
  const u16* Bt = Wt + (size_t)blockIdx.z * DM * DM;
  int n0 = blockIdx.x * 128, m0 = blockIdx.y * 128;
  f32x4 acc[4][4] = {};
  gemm_core(X, Bt, m0, n0, As, Bs, acc);
  int lane = threadIdx.x & 63, wave = threadIdx.x >> 6;
  int l15 = lane & 15, quad = lane >> 4;
  int wm = (wave >> 1) * 64, wn = (wave & 1) * 64;
  if (blockIdx.z == 2) {
    int h = n0 >> 7;
#pragma unroll
    for (int mt = 0; mt < 4; ++mt)
#pragma unroll
      for (int nt = 0; nt < 4; ++nt) {
        int tok = m0 + wm + mt * 16 + quad * 4;
        int d = wn + nt * 16 + l15;
        int b = tok >> 11, sx = tok & (SEQ - 1);
        u16* dp = &Vto[((size_t)(b * NH + h) * HD + d) * SEQ + sx];
        *(u32*)&dp[0] = pack2(acc[mt][nt][0], acc[mt][nt][1]);
        *(u32*)&dp[2] = pack2(acc[mt][nt][2], acc[mt][nt][3]);
      }
  } else {
    u16* C = blockIdx.z == 0 ? Qo : Ko;
#pragma unroll
    for (int mt = 0; mt < 4; ++mt)
#pragma unroll
      for (int nt = 0; nt < 4; ++nt)
#pragma unroll
        for (int r = 0; r < 4; ++r)
          C[(size_t)(m0 + wm + mt * 16 + quad * 4 + r) * DM + n0 + wn + nt * 16 + l15]
              = f2bf(acc[mt][nt][r]);
  }
}

__global__ __launch_bounds__(256) void proj_gemm(const u16* __restrict__ A, const u16* __restrict__ Wt,
                                                 float* __restrict__ C) {
  __shared__ u16 As[128 * 64];
  __shared__ u16 Bs[128 * 64];
  int n0 = blockIdx.x * 128, m0 = blockIdx.y * 128;
  f32x4 acc[4][4] = {};
  gemm_core(A, Wt, m0, n0, As, Bs, acc);
  int lane = threadIdx.x & 63, wave = threadIdx.x >> 6;
  int l15 = lane & 15, quad = lane >> 4;
  int wm = (wave >> 1) * 64, wn = (wave & 1) * 64;
#pragma unroll
  for (int mt = 0; mt < 4; ++mt)
#pragma unroll
    for (int nt = 0; nt < 4; ++nt)
#pragma unroll
      for (int r = 0; r < 4; ++r)
        C[(size_t)(m0 + wm + mt * 16 + quad * 4 + r) * DM + n0 + wn + nt * 16 + l15] = acc[mt][nt][r];
}

// ---------------- RoPE in-place on Q (y=0) and K (y=1) ----------------
__global__ __launch_bounds__(256) void rope_k(u16* __restrict__ Q, u16* __restrict__ K,
                                              const int* __restrict__ pos) {
  uint32_t idx = blockIdx.x * 256 + threadIdx.x;
  int i = idx & 63;
  int h = (idx >> 6) & 15;
  int s = (idx >> 10) & 2047;
  int b = idx >> 21;
  u16* P = (blockIdx.y == 0) ? Q : K;
  int p = pos[b * SEQ + s];
  float inv = powf(10000.0f, -(float)i * (1.0f / 64.0f));
  float ang = (float)p * inv;
  float sn, cs;
  sincosf(ang, &sn, &cs);
  size_t base = ((size_t)(b * SEQ + s)) * DM + h * HD;
  float x1 = bf2f(P[base + i]), x2 = bf2f(P[base + 64 + i]);
  P[base + i] = f2bf(x1 * cs - x2 * sn);
  P[base + 64 + i] = f2bf(x2 * cs + x1 * sn);
}

// ---------------- Flash attention, S^T layout ----------------
// Q-tile 64 (wave owns 16 q = 1 tile), K-tile 64. S^T = K.Q^T so softmax state is per
// q=lane&15 (replicated over quads); P^T B-frags built with 16 shuffles; O^T = V^T.P^T.
__global__ __launch_bounds__(256, 4) void attn_k(const u16* __restrict__ Q, const u16* __restrict__ K,
                                                 const u16* __restrict__ Vt, const int* __restrict__ pos,
                                                 u16* __restrict__ AO) {
  __shared__ u16 Ks[64 * 128];   // swizzled: slot = row*16 + (c ^ (row&15))
  __shared__ u16 Vs[128 * 64];   // swizzled: slot = row*8  + (c ^ (row&7))
  __shared__ int pk[64];
  int qt = blockIdx.x, bh = blockIdx.y;
  int b = bh >> 4, h = bh & 15;
  int tid = threadIdx.x, lane = tid & 63, wave = tid >> 6;
  int l15 = lane & 15, quad = lane >> 4;
  const int* posb = pos + b * SEQ;
  int q0w = qt * 64 + wave * 16;

  // Q fragments (B-operand layout == A layout: n=l15, k=quad*8+j), resident in registers
  bf16x8 qf[4];
#pragma unroll
  for (int kk = 0; kk < 4; ++kk)
    qf[kk] = *(const bf16x8*)&Q[(size_t)(b * SEQ + q0w + l15) * DM + h * HD + kk * 32 + quad * 8];
  int pq = posb[q0w + l15];
  int pqmax = posb[qt * 64 + 63];

  float m_i = -1.0e30f, l_i = 0.0f;
  f32x4 oacc[8] = {};   // O^T: row d = dt*16+quad*4+r, col q = l15

  for (int j0 = 0; j0 < SEQ; j0 += 64) {
    if (posb[j0] > pqmax) break;   // sorted positions: all later tiles fully masked
    // stage K (64 keys x 128 d) and V^T (128 d x 64 keys), async, swizzled
#pragma unroll
    for (int i = 0; i < 4; ++i) {
      int s = i * 256 + tid;
      { int row = s >> 4, c = (s & 15) ^ (row & 15);
        gl2lds16(&K[(size_t)(b * SEQ + j0 + row) * DM + h * HD + c * 8], &Ks[(s & ~63) * 8]); }
      { int row = s >> 3, c = (s & 7) ^ (row & 7);
        gl2lds16(&Vt[((size_t)(b * NH + h) * HD + row) * SEQ + j0 + c * 8], &Vs[(s & ~63) * 8]); }
    }
    if (tid < 64) pk[tid] = posb[j0 + tid];
    __syncthreads();

    // S^T[key][q]: sacc[kt] element r -> key = kt*16 + quad*4 + r, q = l15
    f32x4 sacc[4] = {};
#pragma unroll
    for (int kk = 0; kk < 4; ++kk) {
      bf16x8 kf[4];
#pragma unroll
      for (int kt = 0; kt < 4; ++kt) {
        int row = kt * 16 + l15;
        int c = (kk * 4 + quad) ^ (row & 15);
        kf[kt] = *(const bf16x8*)&Ks[row * 128 + c * 8];
      }
#pragma unroll
      for (int kt = 0; kt < 4; ++kt)
        sacc[kt] = __builtin_amdgcn_mfma_f32_16x16x32_bf16(kf[kt], qf[kk], sacc[kt], 0, 0, 0);
    }

    // mask + scale (key positions broadcast-read from LDS)
    int4 pkv[4];
#pragma unroll
    for (int kt = 0; kt < 4; ++kt) pkv[kt] = *(const int4*)&pk[kt * 16 + quad * 4];
    float mx = -3.0e38f;
#pragma unroll
    for (int kt = 0; kt < 4; ++kt) {
      const int* pr = (const int*)&pkv[kt];
#pragma unroll
      for (int r = 0; r < 4; ++r) {
        float s = sacc[kt][r] * SM_SCALE;
        s = (pq >= pr[r]) ? s : -1.0e30f;
        sacc[kt][r] = s;
        mx = fmaxf(mx, s);
      }
    }
    // column (q) reduction: in-lane 16 keys done above; cross-quad = 2 shuffles
    mx = fmaxf(mx, __shfl_xor(mx, 16));
    mx = fmaxf(mx, __shfl_xor(mx, 32));
    float mn = fmaxf(m_i, mx);
    float al = __expf(m_i - mn);
    m_i = mn;
    float rs = 0.0f;
    u32 pb[4][2];   // packed bf16 P pairs: pb[kt][w] = p(r=2w), p(r=2w+1)
#pragma unroll
    for (int kt = 0; kt < 4; ++kt) {
      float p0 = __expf(sacc[kt][0] - mn), p1 = __expf(sacc[kt][1] - mn);
      float p2 = __expf(sacc[kt][2] - mn), p3 = __expf(sacc[kt][3] - mn);
      rs += (p0 + p1) + (p2 + p3);
      pb[kt][0] = pack2(p0, p1);
      pb[kt][1] = pack2(p2, p3);
    }
    rs += __shfl_xor(rs, 16);
    rs += __shfl_xor(rs, 32);
    l_i = l_i * al + rs;
#pragma unroll
    for (int dt = 0; dt < 8; ++dt) oacc[dt] *= al;

    // O^T += V^T . P^T ; P^T B-frag word w holds keys kk*32+quad*8+{2w,2w+1}
    int base0 = l15 + ((quad & 1) << 5);
    bool hi = (quad >> 1) != 0;
#pragma unroll
    for (int kk = 0; kk < 2; ++kk) {
      u32 w[4];
#pragma unroll
      for (int wd = 0; wd < 4; ++wd) {
        int src = base0 + ((wd >> 1) << 4);
        u32 va = __shfl(pb[kk * 2 + 0][wd & 1], src);
        u32 vb = __shfl(pb[kk * 2 + 1][wd & 1], src);
        w[wd] = hi ? vb : va;
      }
      union { bf16x8 v; u32 u[4]; } pt;
      pt.u[0] = w[0]; pt.u[1] = w[1]; pt.u[2] = w[2]; pt.u[3] = w[3];
#pragma unroll
      for (int dt = 0; dt < 8; ++dt) {
        int row = dt * 16 + l15;
        int c = (kk * 4 + quad) ^ (row & 7);
        bf16x8 vf = *(const bf16x8*)&Vs[row * 64 + c * 8];
        oacc[dt] = __builtin_amdgcn_mfma_f32_16x16x32_bf16(vf, pt.v, oacc[dt], 0, 0, 0);
      }
    }
    __syncthreads();
  }

  // epilogue: O[q][d] = O^T / l, packed u32 stores (r-pairs are d-adjacent)
  float inv = 1.0f / l_i;
  u16* aop = &AO[(size_t)(b * SEQ + q0w + l15) * DM + h * HD];
#pragma unroll
  for (int dt = 0; dt < 8; ++dt) {
    int col = dt * 16 + quad * 4;
    *(u32*)&aop[col]     = pack2(oacc[dt][0] * inv, oacc[dt][1] * inv);
    *(u32*)&aop[col + 2] = pack2(oacc[dt][2] * inv, oacc[dt][3] * inv);
  }
}

extern "C" void kernel_launch(void* const* d_in, const int* in_sizes, int n_in,
                              void* d_out, int out_size, void* d_ws, size_t ws_size,
                              hipStream_t stream) {
  const float* x  = (const float*)d_in[0];
  const float* Wq = (const float*)d_in[1];
  const float* Wk = (const float*)d_in[2];
  const float* Wv = (const float*)d_in[3];
  const float* Wo = (const float*)d_in[4];
  const int*  pos = (const int*)d_in[5];
  float* out = (float*)d_out;

  u16* ws  = (u16*)d_ws;
  u16* xb  = ws;                                   // 4096*2048
  u16* wt  = xb  + (size_t)4096 * 2048;            // 4 * 2048*2048 transposed (N,K)
  u16* qb  = wt  + (size_t)4 * 2048 * 2048;
  u16* kb  = qb  + (size_t)4096 * 2048;
  u16* vtb = kb  + (size_t)4096 * 2048;            // V^T (b,h,d,s) written by qkv_gemm z=2
  u16* aob = vtb + (size_t)4096 * 2048;            // 112 MiB total

  cvt_x<<<8192, 256, 0, stream>>>(x, xb);
  wtrans<<<dim3(64, 64, 4), dim3(32, 8), 0, stream>>>(Wq, Wk, Wv, Wo, wt);
  qkv_gemm<<<dim3(16, 32, 3), 256, 0, stream>>>(xb, wt, qb, kb, vtb);
  rope_k<<<dim3(16384, 2), 256, 0, stream>>>(qb, kb, pos);
  attn_k<<<dim3(32, 32), 256, 0, stream>>>(qb, kb, vtb, pos, aob);
  proj_gemm<<<dim3(16, 32), 256, 0, stream>>>(aob, wt + (size_t)3 * 2048 * 2048, out);
}

// Round 3
// 475.917 us; speedup vs baseline: 1.3080x; 1.0221x over previous
//
#include <hip/hip_runtime.h>
#include <stdint.h>

// R3: attn_k double-buffered staging (prefetch j+1 after the barrier that publishes j,
//     ONE barrier per iteration -> HBM/L3 latency overlapped by compute), LPT block order
//     (long q-tiles first), rope powf->exp2f. GEMMs unchanged (m97 structure).

typedef unsigned short u16;
typedef unsigned int u32;
typedef __attribute__((ext_vector_type(8))) short bf16x8;
typedef __attribute__((ext_vector_type(4))) float f32x4;

#define SEQ 2048
#define DM 2048
#define NH 16
#define HD 128
#define SM_SCALE 0.08838834764831845f   // 1/sqrt(128)

__device__ __forceinline__ u16 f2bf(float f) {
  union { float f; uint32_t u; } v; v.f = f;
  uint32_t u = v.u + 0x7fffu + ((v.u >> 16) & 1u);   // RNE
  return (u16)(u >> 16);
}
__device__ __forceinline__ float bf2f(u16 h) {
  union { uint32_t u; float f; } v; v.u = ((uint32_t)h) << 16; return v.f;
}
__device__ __forceinline__ u32 pack2(float a, float b) {
  return (u32)f2bf(a) | ((u32)f2bf(b) << 16);
}

// async global->LDS, 16B per lane. LDS dest is wave-uniform base + lane*16.
__device__ __forceinline__ void gl2lds16(const void* g, void* l) {
  __builtin_amdgcn_global_load_lds(
      (const __attribute__((address_space(1))) uint32_t*)g,
      (__attribute__((address_space(3))) uint32_t*)l, 16, 0, 0);
}

// ---------------- elementwise fp32 -> bf16 of x ----------------
__global__ __launch_bounds__(256) void cvt_x(const float* __restrict__ x, u16* __restrict__ xb) {
  int i = blockIdx.x * 256 + threadIdx.x;
  float4 v = ((const float4*)x)[i];
  uint2 r;
  r.x = pack2(v.x, v.y);
  r.y = pack2(v.z, v.w);
  ((uint2*)xb)[i] = r;
}

// ---------------- W (K,N) fp32 -> Wt (N,K) bf16, tiled transpose ----------------
__global__ __launch_bounds__(256) void wtrans(const float* __restrict__ w0, const float* __restrict__ w1,
                                              const float* __restrict__ w2, const float* __restrict__ w3,
                                              u16* __restrict__ dst) {
  const float* W = blockIdx.z == 0 ? w0 : blockIdx.z == 1 ? w1 : blockIdx.z == 2 ? w2 : w3;
  u16* D = dst + (size_t)blockIdx.z * DM * DM;
  int k0 = blockIdx.x * 32, n0 = blockIdx.y * 32;
  __shared__ u16 t[32][33];
  int tx = threadIdx.x, ty = threadIdx.y;   // (32,8)
#pragma unroll
  for (int i = 0; i < 32; i += 8)
    t[ty + i][tx] = f2bf(W[(size_t)(k0 + ty + i) * DM + n0 + tx]);
  __syncthreads();
#pragma unroll
  for (int i = 0; i < 32; i += 8)
    D[(size_t)(n0 + ty + i) * DM + k0 + tx] = t[tx][ty + i];
}

// ---------------- 128x128 (BK=64) bf16 MFMA GEMM core, global_load_lds staging ----------------
__device__ __forceinline__ void gemm_core(const u16* __restrict__ A, const u16* __restrict__ Bt,
                                          int m0, int n0, u16* As, u16* Bs, f32x4 acc[4][4]) {
  int tid = threadIdx.x, lane = tid & 63;
  int l15 = lane & 15, quad = lane >> 4;
  int wave = tid >> 6;
  int wm = (wave >> 1) * 64, wn = (wave & 1) * 64;
  for (int k0 = 0; k0 < DM; k0 += 64) {
#pragma unroll
    for (int i = 0; i < 4; ++i) {
      int s = i * 256 + tid;
      int row = s >> 3, c = (s & 7) ^ (row & 7);
      gl2lds16(&A[(size_t)(m0 + row) * DM + k0 + c * 8], &As[(s & ~63) * 8]);
      gl2lds16(&Bt[(size_t)(n0 + row) * DM + k0 + c * 8], &Bs[(s & ~63) * 8]);
    }
    __syncthreads();
#pragma unroll
    for (int kk = 0; kk < 2; ++kk) {
      bf16x8 af[4], bfr[4];
#pragma unroll
      for (int mt = 0; mt < 4; ++mt) {
        int row = wm + mt * 16 + l15;
        int c = (kk * 4 + quad) ^ (row & 7);
        af[mt] = *(const bf16x8*)&As[row * 64 + c * 8];
      }
#pragma unroll
      for (int nt = 0; nt < 4; ++nt) {
        int row = wn + nt * 16 + l15;
        int c = (kk * 4 + quad) ^ (row & 7);
        bfr[nt] = *(const bf16x8*)&Bs[row * 64 + c * 8];
      }
#pragma unroll
      for (int mt = 0; mt < 4; ++mt)
#pragma unroll
        for (int nt = 0; nt < 4; ++nt)
          acc[mt][nt] = __builtin_amdgcn_mfma_f32_16x16x32_bf16(af[mt], bfr[nt], acc[mt][nt], 0, 0, 0);
    }
    __syncthreads();
  }
}

// z=0 -> Q, z=1 -> K (row-major bf16), z=2 -> V stored TRANSPOSED into Vt (b,h,d,s)
__global__ __launch_bounds__(256) void qkv_gemm(const u16* __restrict__ X, const u16* __restrict__ Wt,
                                                u16* __restrict__ Qo, u16* __restrict__ Ko,
                                                u16* __restrict__ Vto) {
  __shared__ u16 As[128 * 64];
  __shared__ u16 Bs[128 * 64];
  const u16* Bt = Wt + (size_t)blockIdx.z * DM * DM;
  int n0 = blockIdx.x * 128, m0 = blockIdx.y * 128;
  f32x4 acc[4][4] = {};
  gemm_core(X, Bt, m0, n0, As, Bs, acc);
  int lane = threadIdx.x & 63, wave = threadIdx.x >> 6;
  int l15 = lane & 15, quad = lane >> 4;
  int wm = (wave >> 1) * 64, wn = (wave & 1) * 64;
  if (blockIdx.z == 2) {
    int h = n0 >> 7;
#pragma unroll
    for (int mt = 0; mt < 4; ++mt)
#pragma unroll
      for (int nt = 0; nt < 4; ++nt) {
        int tok = m0 + wm + mt * 16 + quad * 4;
        int d = wn + nt * 16 + l15;
        int b = tok >> 11, sx = tok & (SEQ - 1);
        u16* dp = &Vto[((size_t)(b * NH + h) * HD + d) * SEQ + sx];
        *(u32*)&dp[0] = pack2(acc[mt][nt][0], acc[mt][nt][1]);
        *(u32*)&dp[2] = pack2(acc[mt][nt][2], acc[mt][nt][3]);
      }
  } else {
    u16* C = blockIdx.z == 0 ? Qo : Ko;
#pragma unroll
    for (int mt = 0; mt < 4; ++mt)
#pragma unroll
      for (int nt = 0; nt < 4; ++nt)
#pragma unroll
        for (int r = 0; r < 4; ++r)
          C[(size_t)(m0 + wm + mt * 16 + quad * 4 + r) * DM + n0 + wn + nt * 16 + l15]
              = f2bf(acc[mt][nt][r]);
  }
}

__global__ __launch_bounds__(256) void proj_gemm(const u16* __restrict__ A, const u16* __restrict__ Wt,
                                                 float* __restrict__ C) {
  __shared__ u16 As[128 * 64];
  __shared__ u16 Bs[128 * 64];
  int n0 = blockIdx.x * 128, m0 = blockIdx.y * 128;
  f32x4 acc[4][4] = {};
  gemm_core(A, Wt, m0, n0, As, Bs, acc);
  int lane = threadIdx.x & 63, wave = threadIdx.x >> 6;
  int l15 = lane & 15, quad = lane >> 4;
  int wm = (wave >> 1) * 64, wn = (wave & 1) * 64;
#pragma unroll
  for (int mt = 0; mt < 4; ++mt)
#pragma unroll
    for (int nt = 0; nt < 4; ++nt)
#pragma unroll
      for (int r = 0; r < 4; ++r)
        C[(size_t)(m0 + wm + mt * 16 + quad * 4 + r) * DM + n0 + wn + nt * 16 + l15] = acc[mt][nt][r];
}

// ---------------- RoPE in-place on Q (y=0) and K (y=1) ----------------
__global__ __launch_bounds__(256) void rope_k(u16* __restrict__ Q, u16* __restrict__ K,
                                              const int* __restrict__ pos) {
  uint32_t idx = blockIdx.x * 256 + threadIdx.x;
  int i = idx & 63;
  int h = (idx >> 6) & 15;
  int s = (idx >> 10) & 2047;
  int b = idx >> 21;
  u16* P = (blockIdx.y == 0) ? Q : K;
  int p = pos[b * SEQ + s];
  // 10000^(-i/64) = exp2(-i * log2(10000)/64); exp2f -> v_exp_f32 (1 ulp), powf was libm-slow
  float inv = exp2f((float)i * -0.20762051f);
  float ang = (float)p * inv;
  float sn, cs;
  sincosf(ang, &sn, &cs);   // precise: |ang| up to ~8192 rad, protect absmax margin
  size_t base = ((size_t)(b * SEQ + s)) * DM + h * HD;
  float x1 = bf2f(P[base + i]), x2 = bf2f(P[base + 64 + i]);
  P[base + i] = f2bf(x1 * cs - x2 * sn);
  P[base + 64 + i] = f2bf(x2 * cs + x1 * sn);
}

// ---------------- Flash attention, S^T layout, double-buffered staging ----------------
__global__ __launch_bounds__(256) void attn_k(const u16* __restrict__ Q, const u16* __restrict__ K,
                                              const u16* __restrict__ Vt, const int* __restrict__ pos,
                                              u16* __restrict__ AO) {
  __shared__ u16 Ks[2][64 * 128];   // swizzled: slot = row*16 + (c ^ (row&15))
  __shared__ u16 Vs[2][128 * 64];   // swizzled: slot = row*8  + (c ^ (row&7))
  __shared__ int pk[2][64];
  int qt = (int)gridDim.x - 1 - (int)blockIdx.x;   // LPT: long q-tiles first
  int bh = blockIdx.y;
  int b = bh >> 4, h = bh & 15;
  int tid = threadIdx.x, lane = tid & 63, wave = tid >> 6;
  int l15 = lane & 15, quad = lane >> 4;
  const int* posb = pos + b * SEQ;
  int q0w = qt * 64 + wave * 16;
  const u16* Kbase = &K[(size_t)(b * SEQ) * DM + h * HD];
  const u16* Vbase = &Vt[(size_t)(b * NH + h) * HD * SEQ];

  // Q fragments resident in registers (B-operand layout: n=l15, k=quad*8+j)
  bf16x8 qf[4];
#pragma unroll
  for (int kk = 0; kk < 4; ++kk)
    qf[kk] = *(const bf16x8*)&Q[(size_t)(b * SEQ + q0w + l15) * DM + h * HD + kk * 32 + quad * 8];
  int pq = posb[q0w + l15];
  int pqmax = posb[qt * 64 + 63];

  // number of K-tiles this block needs (sorted positions)
  int ntile = 1;
  while (ntile < 32 && posb[ntile * 64] <= pqmax) ++ntile;

  // stage tile 0 into buffer 0
  {
    int j0 = 0;
#pragma unroll
    for (int i = 0; i < 4; ++i) {
      int s = i * 256 + tid;
      { int row = s >> 4, c = (s & 15) ^ (row & 15);
        gl2lds16(&Kbase[(size_t)(j0 + row) * DM + c * 8], &Ks[0][(s & ~63) * 8]); }
      { int row = s >> 3, c = (s & 7) ^ (row & 7);
        gl2lds16(&Vbase[(size_t)row * SEQ + j0 + c * 8], &Vs[0][(s & ~63) * 8]); }
    }
    if (tid < 64) pk[0][tid] = posb[j0 + tid];
  }

  float m_i = -1.0e30f, l_i = 0.0f;
  f32x4 oacc[8] = {};   // O^T: row d = dt*16+quad*4+r, col q = l15

  for (int j = 0; j < ntile; ++j) {
    int cur = j & 1;
    __syncthreads();   // publishes buffer cur (drains prefetch vmcnt); buffer cur^1 free

    // prefetch next tile into the alternate buffer — latency overlaps compute below
    if (j + 1 < ntile) {
      int j0n = (j + 1) * 64, alt = cur ^ 1;
#pragma unroll
      for (int i = 0; i < 4; ++i) {
        int s = i * 256 + tid;
        { int row = s >> 4, c = (s & 15) ^ (row & 15);
          gl2lds16(&Kbase[(size_t)(j0n + row) * DM + c * 8], &Ks[alt][(s & ~63) * 8]); }
        { int row = s >> 3, c = (s & 7) ^ (row & 7);
          gl2lds16(&Vbase[(size_t)row * SEQ + j0n + c * 8], &Vs[alt][(s & ~63) * 8]); }
      }
      if (tid < 64) pk[alt][tid] = posb[j0n + tid];
    }

    // S^T[key][q]: sacc[kt] element r -> key = kt*16 + quad*4 + r, q = l15
    f32x4 sacc[4] = {};
#pragma unroll
    for (int kk = 0; kk < 4; ++kk) {
      bf16x8 kf[4];
#pragma unroll
      for (int kt = 0; kt < 4; ++kt) {
        int row = kt * 16 + l15;
        int c = (kk * 4 + quad) ^ (row & 15);
        kf[kt] = *(const bf16x8*)&Ks[cur][row * 128 + c * 8];
      }
#pragma unroll
      for (int kt = 0; kt < 4; ++kt)
        sacc[kt] = __builtin_amdgcn_mfma_f32_16x16x32_bf16(kf[kt], qf[kk], sacc[kt], 0, 0, 0);
    }

    // mask + scale
    int4 pkv[4];
#pragma unroll
    for (int kt = 0; kt < 4; ++kt) pkv[kt] = *(const int4*)&pk[cur][kt * 16 + quad * 4];
    float mx = -3.0e38f;
#pragma unroll
    for (int kt = 0; kt < 4; ++kt) {
      const int* pr = (const int*)&pkv[kt];
#pragma unroll
      for (int r = 0; r < 4; ++r) {
        float s = sacc[kt][r] * SM_SCALE;
        s = (pq >= pr[r]) ? s : -1.0e30f;
        sacc[kt][r] = s;
        mx = fmaxf(mx, s);
      }
    }
    // column (q) reduction: cross-quad = 2 shuffles
    mx = fmaxf(mx, __shfl_xor(mx, 16));
    mx = fmaxf(mx, __shfl_xor(mx, 32));
    float mn = fmaxf(m_i, mx);
    float al = __expf(m_i - mn);
    m_i = mn;
    float rs = 0.0f;
    u32 pb[4][2];
#pragma unroll
    for (int kt = 0; kt < 4; ++kt) {
      float p0 = __expf(sacc[kt][0] - mn), p1 = __expf(sacc[kt][1] - mn);
      float p2 = __expf(sacc[kt][2] - mn), p3 = __expf(sacc[kt][3] - mn);
      rs += (p0 + p1) + (p2 + p3);
      pb[kt][0] = pack2(p0, p1);
      pb[kt][1] = pack2(p2, p3);
    }
    rs += __shfl_xor(rs, 16);
    rs += __shfl_xor(rs, 32);
    l_i = l_i * al + rs;
#pragma unroll
    for (int dt = 0; dt < 8; ++dt) oacc[dt] *= al;

    // O^T += V^T . P^T ; P^T B-frag built in-register via shuffles
    int base0 = l15 + ((quad & 1) << 5);
    bool hi = (quad >> 1) != 0;
#pragma unroll
    for (int kk = 0; kk < 2; ++kk) {
      u32 w[4];
#pragma unroll
      for (int wd = 0; wd < 4; ++wd) {
        int src = base0 + ((wd >> 1) << 4);
        u32 va = __shfl(pb[kk * 2 + 0][wd & 1], src);
        u32 vb = __shfl(pb[kk * 2 + 1][wd & 1], src);
        w[wd] = hi ? vb : va;
      }
      union { bf16x8 v; u32 u[4]; } pt;
      pt.u[0] = w[0]; pt.u[1] = w[1]; pt.u[2] = w[2]; pt.u[3] = w[3];
#pragma unroll
      for (int dt = 0; dt < 8; ++dt) {
        int row = dt * 16 + l15;
        int c = (kk * 4 + quad) ^ (row & 7);
        bf16x8 vf = *(const bf16x8*)&Vs[cur][row * 64 + c * 8];
        oacc[dt] = __builtin_amdgcn_mfma_f32_16x16x32_bf16(vf, pt.v, oacc[dt], 0, 0, 0);
      }
    }
    // no second barrier: buffer cur is only overwritten after the NEXT top-of-loop barrier
  }

  // epilogue: O[q][d] = O^T / l, packed u32 stores
  float inv = 1.0f / l_i;
  u16* aop = &AO[(size_t)(b * SEQ + q0w + l15) * DM + h * HD];
#pragma unroll
  for (int dt = 0; dt < 8; ++dt) {
    int col = dt * 16 + quad * 4;
    *(u32*)&aop[col]     = pack2(oacc[dt][0] * inv, oacc[dt][1] * inv);
    *(u32*)&aop[col + 2] = pack2(oacc[dt][2] * inv, oacc[dt][3] * inv);
  }
}

extern "C" void kernel_launch(void* const* d_in, const int* in_sizes, int n_in,
                              void* d_out, int out_size, void* d_ws, size_t ws_size,
                              hipStream_t stream) {
  const float* x  = (const float*)d_in[0];
  const float* Wq = (const float*)d_in[1];
  const float* Wk = (const float*)d_in[2];
  const float* Wv = (const float*)d_in[3];
  const float* Wo = (const float*)d_in[4];
  const int*  pos = (const int*)d_in[5];
  float* out = (float*)d_out;

  u16* ws  = (u16*)d_ws;
  u16* xb  = ws;                                   // 4096*2048
  u16* wt  = xb  + (size_t)4096 * 2048;            // 4 * 2048*2048 transposed (N,K)
  u16* qb  = wt  + (size_t)4 * 2048 * 2048;
  u16* kb  = qb  + (size_t)4096 * 2048;
  u16* vtb = kb  + (size_t)4096 * 2048;            // V^T (b,h,d,s) written by qkv_gemm z=2
  u16* aob = vtb + (size_t)4096 * 2048;            // 112 MiB total

  cvt_x<<<8192, 256, 0, stream>>>(x, xb);
  wtrans<<<dim3(64, 64, 4), dim3(32, 8), 0, stream>>>(Wq, Wk, Wv, Wo, wt);
  qkv_gemm<<<dim3(16, 32, 3), 256, 0, stream>>>(xb, wt, qb, kb, vtb);
  rope_k<<<dim3(16384, 2), 256, 0, stream>>>(qb, kb, pos);
  attn_k<<<dim3(32, 32), 256, 0, stream>>>(qb, kb, vtb, pos, aob);
  proj_gemm<<<dim3(16, 32), 256, 0, stream>>>(aob, wt + (size_t)3 * 2048 * 2048, out);
}

// Round 4
// 469.510 us; speedup vs baseline: 1.3259x; 1.0136x over previous
//
#include <hip/hip_runtime.h>
#include <stdint.h>

// R4: attn_k — 2 q-tiles (32 q) per wave: every K/V LDS fragment feeds 2 MFMAs
//     (MFMA:ds_read ratio 1:2.5 -> 2:1), softmax overhead amortized 2x. Keep dbuf
//     single-barrier (at 66KB LDS the 512 blocks are all co-resident regardless).
//     Complementary q-tile remap so paired-resident blocks have ~constant total work.

typedef unsigned short u16;
typedef unsigned int u32;
typedef __attribute__((ext_vector_type(8))) short bf16x8;
typedef __attribute__((ext_vector_type(4))) float f32x4;

#define SEQ 2048
#define DM 2048
#define NH 16
#define HD 128
#define SM_SCALE 0.08838834764831845f   // 1/sqrt(128)

__device__ __forceinline__ u16 f2bf(float f) {
  union { float f; uint32_t u; } v; v.f = f;
  uint32_t u = v.u + 0x7fffu + ((v.u >> 16) & 1u);   // RNE
  return (u16)(u >> 16);
}
__device__ __forceinline__ float bf2f(u16 h) {
  union { uint32_t u; float f; } v; v.u = ((uint32_t)h) << 16; return v.f;
}
__device__ __forceinline__ u32 pack2(float a, float b) {
  return (u32)f2bf(a) | ((u32)f2bf(b) << 16);
}

// async global->LDS, 16B per lane. LDS dest is wave-uniform base + lane*16.
__device__ __forceinline__ void gl2lds16(const void* g, void* l) {
  __builtin_amdgcn_global_load_lds(
      (const __attribute__((address_space(1))) uint32_t*)g,
      (__attribute__((address_space(3))) uint32_t*)l, 16, 0, 0);
}

// ---------------- elementwise fp32 -> bf16 of x ----------------
__global__ __launch_bounds__(256) void cvt_x(const float* __restrict__ x, u16* __restrict__ xb) {
  int i = blockIdx.x * 256 + threadIdx.x;
  float4 v = ((const float4*)x)[i];
  uint2 r;
  r.x = pack2(v.x, v.y);
  r.y = pack2(v.z, v.w);
  ((uint2*)xb)[i] = r;
}

// ---------------- W (K,N) fp32 -> Wt (N,K) bf16, tiled transpose ----------------
__global__ __launch_bounds__(256) void wtrans(const float* __restrict__ w0, const float* __restrict__ w1,
                                              const float* __restrict__ w2, const float* __restrict__ w3,
                                              u16* __restrict__ dst) {
  const float* W = blockIdx.z == 0 ? w0 : blockIdx.z == 1 ? w1 : blockIdx.z == 2 ? w2 : w3;
  u16* D = dst + (size_t)blockIdx.z * DM * DM;
  int k0 = blockIdx.x * 32, n0 = blockIdx.y * 32;
  __shared__ u16 t[32][33];
  int tx = threadIdx.x, ty = threadIdx.y;   // (32,8)
#pragma unroll
  for (int i = 0; i < 32; i += 8)
    t[ty + i][tx] = f2bf(W[(size_t)(k0 + ty + i) * DM + n0 + tx]);
  __syncthreads();
#pragma unroll
  for (int i = 0; i < 32; i += 8)
    D[(size_t)(n0 + ty + i) * DM + k0 + tx] = t[tx][ty + i];
}

// ---------------- 128x128 (BK=64) bf16 MFMA GEMM core, global_load_lds staging ----------------
__device__ __forceinline__ void gemm_core(const u16* __restrict__ A, const u16* __restrict__ Bt,
                                          int m0, int n0, u16* As, u16* Bs, f32x4 acc[4][4]) {
  int tid = threadIdx.x, lane = tid & 63;
  int l15 = lane & 15, quad = lane >> 4;
  int wave = tid >> 6;
  int wm = (wave >> 1) * 64, wn = (wave & 1) * 64;
  for (int k0 = 0; k0 < DM; k0 += 64) {
#pragma unroll
    for (int i = 0; i < 4; ++i) {
      int s = i * 256 + tid;
      int row = s >> 3, c = (s & 7) ^ (row & 7);
      gl2lds16(&A[(size_t)(m0 + row) * DM + k0 + c * 8], &As[(s & ~63) * 8]);
      gl2lds16(&Bt[(size_t)(n0 + row) * DM + k0 + c * 8], &Bs[(s & ~63) * 8]);
    }
    __syncthreads();
#pragma unroll
    for (int kk = 0; kk < 2; ++kk) {
      bf16x8 af[4], bfr[4];
#pragma unroll
      for (int mt = 0; mt < 4; ++mt) {
        int row = wm + mt * 16 + l15;
        int c = (kk * 4 + quad) ^ (row & 7);
        af[mt] = *(const bf16x8*)&As[row * 64 + c * 8];
      }
#pragma unroll
      for (int nt = 0; nt < 4; ++nt) {
        int row = wn + nt * 16 + l15;
        int c = (kk * 4 + quad) ^ (row & 7);
        bfr[nt] = *(const bf16x8*)&Bs[row * 64 + c * 8];
      }
#pragma unroll
      for (int mt = 0; mt < 4; ++mt)
#pragma unroll
        for (int nt = 0; nt < 4; ++nt)
          acc[mt][nt] = __builtin_amdgcn_mfma_f32_16x16x32_bf16(af[mt], bfr[nt], acc[mt][nt], 0, 0, 0);
    }
    __syncthreads();
  }
}

// z=0 -> Q, z=1 -> K (row-major bf16), z=2 -> V stored TRANSPOSED into Vt (b,h,d,s)
__global__ __launch_bounds__(256) void qkv_gemm(const u16* __restrict__ X, const u16* __restrict__ Wt,
                                                u16* __restrict__ Qo, u16* __restrict__ Ko,
                                                u16* __restrict__ Vto) {
  __shared__ u16 As[128 * 64];
  __shared__ u16 Bs[128 * 64];
  const u16* Bt = Wt + (size_t)blockIdx.z * DM * DM;
  int n0 = blockIdx.x * 128, m0 = blockIdx.y * 128;
  f32x4 acc[4][4] = {};
  gemm_core(X, Bt, m0, n0, As, Bs, acc);
  int lane = threadIdx.x & 63, wave = threadIdx.x >> 6;
  int l15 = lane & 15, quad = lane >> 4;
  int wm = (wave >> 1) * 64, wn = (wave & 1) * 64;
  if (blockIdx.z == 2) {
    int h = n0 >> 7;
#pragma unroll
    for (int mt = 0; mt < 4; ++mt)
#pragma unroll
      for (int nt = 0; nt < 4; ++nt) {
        int tok = m0 + wm + mt * 16 + quad * 4;
        int d = wn + nt * 16 + l15;
        int b = tok >> 11, sx = tok & (SEQ - 1);
        u16* dp = &Vto[((size_t)(b * NH + h) * HD + d) * SEQ + sx];
        *(u32*)&dp[0] = pack2(acc[mt][nt][0], acc[mt][nt][1]);
        *(u32*)&dp[2] = pack2(acc[mt][nt][2], acc[mt][nt][3]);
      }
  } else {
    u16* C = blockIdx.z == 0 ? Qo : Ko;
#pragma unroll
    for (int mt = 0; mt < 4; ++mt)
#pragma unroll
      for (int nt = 0; nt < 4; ++nt)
#pragma unroll
        for (int r = 0; r < 4; ++r)
          C[(size_t)(m0 + wm + mt * 16 + quad * 4 + r) * DM + n0 + wn + nt * 16 + l15]
              = f2bf(acc[mt][nt][r]);
  }
}

__global__ __launch_bounds__(256) void proj_gemm(const u16* __restrict__ A, const u16* __restrict__ Wt,
                                                 float* __restrict__ C) {
  __shared__ u16 As[128 * 64];
  __shared__ u16 Bs[128 * 64];
  int n0 = blockIdx.x * 128, m0 = blockIdx.y * 128;
  f32x4 acc[4][4] = {};
  gemm_core(A, Wt, m0, n0, As, Bs, acc);
  int lane = threadIdx.x & 63, wave = threadIdx.x >> 6;
  int l15 = lane & 15, quad = lane >> 4;
  int wm = (wave >> 1) * 64, wn = (wave & 1) * 64;
#pragma unroll
  for (int mt = 0; mt < 4; ++mt)
#pragma unroll
    for (int nt = 0; nt < 4; ++nt)
#pragma unroll
      for (int r = 0; r < 4; ++r)
        C[(size_t)(m0 + wm + mt * 16 + quad * 4 + r) * DM + n0 + wn + nt * 16 + l15] = acc[mt][nt][r];
}

// ---------------- RoPE in-place on Q (y=0) and K (y=1) ----------------
__global__ __launch_bounds__(256) void rope_k(u16* __restrict__ Q, u16* __restrict__ K,
                                              const int* __restrict__ pos) {
  uint32_t idx = blockIdx.x * 256 + threadIdx.x;
  int i = idx & 63;
  int h = (idx >> 6) & 15;
  int s = (idx >> 10) & 2047;
  int b = idx >> 21;
  u16* P = (blockIdx.y == 0) ? Q : K;
  int p = pos[b * SEQ + s];
  float inv = exp2f((float)i * -0.20762051f);   // 10000^(-i/64)
  float ang = (float)p * inv;
  float sn, cs;
  sincosf(ang, &sn, &cs);   // precise: |ang| up to ~8192 rad, protect absmax margin
  size_t base = ((size_t)(b * SEQ + s)) * DM + h * HD;
  float x1 = bf2f(P[base + i]), x2 = bf2f(P[base + 64 + i]);
  P[base + i] = f2bf(x1 * cs - x2 * sn);
  P[base + 64 + i] = f2bf(x2 * cs + x1 * sn);
}

// ---------------- Flash attention: 128-q blocks, 32 q per wave (2 q-tiles) ----------------
// S^T = K.Q^T layout; dbuf staging, one barrier/iter; K/V frags reused across both q-tiles.
__global__ __launch_bounds__(256) void attn_k(const u16* __restrict__ Q, const u16* __restrict__ K,
                                              const u16* __restrict__ Vt, const int* __restrict__ pos,
                                              u16* __restrict__ AO) {
  __shared__ u16 Ks[2][64 * 128];   // swizzled: slot = row*16 + (c ^ (row&15))
  __shared__ u16 Vs[2][128 * 64];   // swizzled: slot = row*8  + (c ^ (row&7))
  __shared__ int pk[2][64];
  // complementary q-tile remap: paired-resident blocks (linear id +-256 <-> b flipped)
  // get qt and 15-qt -> near-constant per-CU work (heuristic; perf-only).
  int bx = blockIdx.x, bh = blockIdx.y;
  int b = bh >> 4, h = bh & 15;
  int qt = b ? (15 - bx) : bx;
  int tid = threadIdx.x, lane = tid & 63, wave = tid >> 6;
  int l15 = lane & 15, quad = lane >> 4;
  const int* posb = pos + b * SEQ;
  int qbase = qt * 128 + wave * 16;        // qi adds +64
  const u16* Kbase = &K[(size_t)(b * SEQ) * DM + h * HD];
  const u16* Vbase = &Vt[(size_t)(b * NH + h) * HD * SEQ];

  // Q fragments resident (B-operand layout: n=l15, k=quad*8+j), 2 q-tiles per wave
  bf16x8 qf[2][4];
  int pq[2];
#pragma unroll
  for (int qi = 0; qi < 2; ++qi) {
#pragma unroll
    for (int kk = 0; kk < 4; ++kk)
      qf[qi][kk] = *(const bf16x8*)&Q[(size_t)(b * SEQ + qbase + qi * 64 + l15) * DM
                                      + h * HD + kk * 32 + quad * 8];
    pq[qi] = posb[qbase + qi * 64 + l15];
  }
  int pqmax = posb[qt * 128 + 127];

  int ntile = 1;
  while (ntile < 32 && posb[ntile * 64] <= pqmax) ++ntile;

  // stage tile 0 into buffer 0
#pragma unroll
  for (int i = 0; i < 4; ++i) {
    int s = i * 256 + tid;
    { int row = s >> 4, c = (s & 15) ^ (row & 15);
      gl2lds16(&Kbase[(size_t)row * DM + c * 8], &Ks[0][(s & ~63) * 8]); }
    { int row = s >> 3, c = (s & 7) ^ (row & 7);
      gl2lds16(&Vbase[(size_t)row * SEQ + c * 8], &Vs[0][(s & ~63) * 8]); }
  }
  if (tid < 64) pk[0][tid] = posb[tid];

  float m_i[2] = {-1.0e30f, -1.0e30f}, l_i[2] = {0.0f, 0.0f};
  f32x4 oacc[2][8] = {};   // O^T per q-tile: row d = dt*16+quad*4+r, col q = l15

  for (int j = 0; j < ntile; ++j) {
    int cur = j & 1;
    __syncthreads();   // publishes buffer cur; buffer cur^1 free for prefetch

    if (j + 1 < ntile) {
      int j0n = (j + 1) * 64, alt = cur ^ 1;
#pragma unroll
      for (int i = 0; i < 4; ++i) {
        int s = i * 256 + tid;
        { int row = s >> 4, c = (s & 15) ^ (row & 15);
          gl2lds16(&Kbase[(size_t)(j0n + row) * DM + c * 8], &Ks[alt][(s & ~63) * 8]); }
        { int row = s >> 3, c = (s & 7) ^ (row & 7);
          gl2lds16(&Vbase[(size_t)row * SEQ + j0n + c * 8], &Vs[alt][(s & ~63) * 8]); }
      }
      if (tid < 64) pk[alt][tid] = posb[j0n + tid];
    }

    // S^T[key][q] for both q-tiles; kf shared
    f32x4 sacc[2][4] = {};
#pragma unroll
    for (int kk = 0; kk < 4; ++kk) {
      bf16x8 kf[4];
#pragma unroll
      for (int kt = 0; kt < 4; ++kt) {
        int row = kt * 16 + l15;
        int c = (kk * 4 + quad) ^ (row & 15);
        kf[kt] = *(const bf16x8*)&Ks[cur][row * 128 + c * 8];
      }
#pragma unroll
      for (int qi = 0; qi < 2; ++qi)
#pragma unroll
        for (int kt = 0; kt < 4; ++kt)
          sacc[qi][kt] = __builtin_amdgcn_mfma_f32_16x16x32_bf16(kf[kt], qf[qi][kk], sacc[qi][kt], 0, 0, 0);
    }

    int4 pkv[4];
#pragma unroll
    for (int kt = 0; kt < 4; ++kt) pkv[kt] = *(const int4*)&pk[cur][kt * 16 + quad * 4];

    u32 pb[2][4][2];
    float al[2];
#pragma unroll
    for (int qi = 0; qi < 2; ++qi) {
      float mx = -3.0e38f;
#pragma unroll
      for (int kt = 0; kt < 4; ++kt) {
        const int* pr = (const int*)&pkv[kt];
#pragma unroll
        for (int r = 0; r < 4; ++r) {
          float s = sacc[qi][kt][r] * SM_SCALE;
          s = (pq[qi] >= pr[r]) ? s : -1.0e30f;
          sacc[qi][kt][r] = s;
          mx = fmaxf(mx, s);
        }
      }
      mx = fmaxf(mx, __shfl_xor(mx, 16));
      mx = fmaxf(mx, __shfl_xor(mx, 32));
      float mn = fmaxf(m_i[qi], mx);
      al[qi] = __expf(m_i[qi] - mn);
      m_i[qi] = mn;
      float rs = 0.0f;
#pragma unroll
      for (int kt = 0; kt < 4; ++kt) {
        float p0 = __expf(sacc[qi][kt][0] - mn), p1 = __expf(sacc[qi][kt][1] - mn);
        float p2 = __expf(sacc[qi][kt][2] - mn), p3 = __expf(sacc[qi][kt][3] - mn);
        rs += (p0 + p1) + (p2 + p3);
        pb[qi][kt][0] = pack2(p0, p1);
        pb[qi][kt][1] = pack2(p2, p3);
      }
      rs += __shfl_xor(rs, 16);
      rs += __shfl_xor(rs, 32);
      l_i[qi] = l_i[qi] * al[qi] + rs;
#pragma unroll
      for (int dt = 0; dt < 8; ++dt) oacc[qi][dt] *= al[qi];
    }

    // O^T += V^T . P^T ; vf shared across both q-tiles
    int base0 = l15 + ((quad & 1) << 5);
    bool hi = (quad >> 1) != 0;
#pragma unroll
    for (int kk = 0; kk < 2; ++kk) {
      bf16x8 vf[8];
#pragma unroll
      for (int dt = 0; dt < 8; ++dt) {
        int row = dt * 16 + l15;
        int c = (kk * 4 + quad) ^ (row & 7);
        vf[dt] = *(const bf16x8*)&Vs[cur][row * 64 + c * 8];
      }
#pragma unroll
      for (int qi = 0; qi < 2; ++qi) {
        u32 w[4];
#pragma unroll
        for (int wd = 0; wd < 4; ++wd) {
          int src = base0 + ((wd >> 1) << 4);
          u32 va = __shfl(pb[qi][kk * 2 + 0][wd & 1], src);
          u32 vb = __shfl(pb[qi][kk * 2 + 1][wd & 1], src);
          w[wd] = hi ? vb : va;
        }
        union { bf16x8 v; u32 u[4]; } pt;
        pt.u[0] = w[0]; pt.u[1] = w[1]; pt.u[2] = w[2]; pt.u[3] = w[3];
#pragma unroll
        for (int dt = 0; dt < 8; ++dt)
          oacc[qi][dt] = __builtin_amdgcn_mfma_f32_16x16x32_bf16(vf[dt], pt.v, oacc[qi][dt], 0, 0, 0);
      }
    }
  }

  // epilogue
#pragma unroll
  for (int qi = 0; qi < 2; ++qi) {
    float inv = 1.0f / l_i[qi];
    u16* aop = &AO[(size_t)(b * SEQ + qbase + qi * 64 + l15) * DM + h * HD];
#pragma unroll
    for (int dt = 0; dt < 8; ++dt) {
      int col = dt * 16 + quad * 4;
      *(u32*)&aop[col]     = pack2(oacc[qi][dt][0] * inv, oacc[qi][dt][1] * inv);
      *(u32*)&aop[col + 2] = pack2(oacc[qi][dt][2] * inv, oacc[qi][dt][3] * inv);
    }
  }
}

extern "C" void kernel_launch(void* const* d_in, const int* in_sizes, int n_in,
                              void* d_out, int out_size, void* d_ws, size_t ws_size,
                              hipStream_t stream) {
  const float* x  = (const float*)d_in[0];
  const float* Wq = (const float*)d_in[1];
  const float* Wk = (const float*)d_in[2];
  const float* Wv = (const float*)d_in[3];
  const float* Wo = (const float*)d_in[4];
  const int*  pos = (const int*)d_in[5];
  float* out = (float*)d_out;

  u16* ws  = (u16*)d_ws;
  u16* xb  = ws;
  u16* wt  = xb  + (size_t)4096 * 2048;
  u16* qb  = wt  + (size_t)4 * 2048 * 2048;
  u16* kb  = qb  + (size_t)4096 * 2048;
  u16* vtb = kb  + (size_t)4096 * 2048;
  u16* aob = vtb + (size_t)4096 * 2048;

  cvt_x<<<8192, 256, 0, stream>>>(x, xb);
  wtrans<<<dim3(64, 64, 4), dim3(32, 8), 0, stream>>>(Wq, Wk, Wv, Wo, wt);
  qkv_gemm<<<dim3(16, 32, 3), 256, 0, stream>>>(xb, wt, qb, kb, vtb);
  rope_k<<<dim3(16384, 2), 256, 0, stream>>>(qb, kb, pos);
  attn_k<<<dim3(16, 32), 256, 0, stream>>>(qb, kb, vtb, pos, aob);
  proj_gemm<<<dim3(16, 32), 256, 0, stream>>>(aob, wt + (size_t)3 * 2048 * 2048, out);
}

// Round 5
// 459.289 us; speedup vs baseline: 1.3554x; 1.0223x over previous
//
#include <hip/hip_runtime.h>
#include <stdint.h>

// R5: attn_k rewrite against iteration-latency serialization:
//  (1) STATIC double buffers (Ks0/Ks1/Vs0/Vs1) + loop unrolled x2 so the DMA dest is
//      compile-time known -> compiler can prove global_load_lds (an LDS write) doesn't
//      alias the ds_reads of the other buffer -> no vmcnt(0) drain inside the iteration.
//  (2) Sorted positions => visible keys are a prefix: per-lane cnt=upper_bound(pos,pos_q)
//      once; in-loop mask = integer compare; interior tiles skip masking (uniform branch).
//      pk[] LDS array deleted.
//  (3) VALU diet: scale folded into exp2f, truncation bf16 pack for P, rescale skip.
// GEMMs / rope / transposes unchanged from R4.

typedef unsigned short u16;
typedef unsigned int u32;
typedef __attribute__((ext_vector_type(8))) short bf16x8;
typedef __attribute__((ext_vector_type(4))) float f32x4;

#define SEQ 2048
#define DM 2048
#define NH 16
#define HD 128
#define SM_SCALE 0.08838834764831845f
#define K2LOG 0.12751743f   // SM_SCALE * log2(e)

__device__ __forceinline__ u16 f2bf(float f) {
  union { float f; uint32_t u; } v; v.f = f;
  uint32_t u = v.u + 0x7fffu + ((v.u >> 16) & 1u);   // RNE
  return (u16)(u >> 16);
}
__device__ __forceinline__ float bf2f(u16 h) {
  union { uint32_t u; float f; } v; v.u = ((uint32_t)h) << 16; return v.f;
}
__device__ __forceinline__ u32 pack2(float a, float b) {
  return (u32)f2bf(a) | ((u32)f2bf(b) << 16);
}
__device__ __forceinline__ u32 pack2_trunc(float a, float b) {   // RTZ: P in [0,1], plenty of margin
  union { float f; u32 u; } x, y; x.f = a; y.f = b;
  return (x.u >> 16) | (y.u & 0xFFFF0000u);
}

// async global->LDS, 16B per lane. LDS dest is wave-uniform base + lane*16.
__device__ __forceinline__ void gl2lds16(const void* g, void* l) {
  __builtin_amdgcn_global_load_lds(
      (const __attribute__((address_space(1))) uint32_t*)g,
      (__attribute__((address_space(3))) uint32_t*)l, 16, 0, 0);
}

// ---------------- elementwise fp32 -> bf16 of x ----------------
__global__ __launch_bounds__(256) void cvt_x(const float* __restrict__ x, u16* __restrict__ xb) {
  int i = blockIdx.x * 256 + threadIdx.x;
  float4 v = ((const float4*)x)[i];
  uint2 r;
  r.x = pack2(v.x, v.y);
  r.y = pack2(v.z, v.w);
  ((uint2*)xb)[i] = r;
}

// ---------------- W (K,N) fp32 -> Wt (N,K) bf16, tiled transpose ----------------
__global__ __launch_bounds__(256) void wtrans(const float* __restrict__ w0, const float* __restrict__ w1,
                                              const float* __restrict__ w2, const float* __restrict__ w3,
                                              u16* __restrict__ dst) {
  const float* W = blockIdx.z == 0 ? w0 : blockIdx.z == 1 ? w1 : blockIdx.z == 2 ? w2 : w3;
  u16* D = dst + (size_t)blockIdx.z * DM * DM;
  int k0 = blockIdx.x * 32, n0 = blockIdx.y * 32;
  __shared__ u16 t[32][33];
  int tx = threadIdx.x, ty = threadIdx.y;   // (32,8)
#pragma unroll
  for (int i = 0; i < 32; i += 8)
    t[ty + i][tx] = f2bf(W[(size_t)(k0 + ty + i) * DM + n0 + tx]);
  __syncthreads();
#pragma unroll
  for (int i = 0; i < 32; i += 8)
    D[(size_t)(n0 + ty + i) * DM + k0 + tx] = t[tx][ty + i];
}

// ---------------- 128x128 (BK=64) bf16 MFMA GEMM core, global_load_lds staging ----------------
__device__ __forceinline__ void gemm_core(const u16* __restrict__ A, const u16* __restrict__ Bt,
                                          int m0, int n0, u16* As, u16* Bs, f32x4 acc[4][4]) {
  int tid = threadIdx.x, lane = tid & 63;
  int l15 = lane & 15, quad = lane >> 4;
  int wave = tid >> 6;
  int wm = (wave >> 1) * 64, wn = (wave & 1) * 64;
  for (int k0 = 0; k0 < DM; k0 += 64) {
#pragma unroll
    for (int i = 0; i < 4; ++i) {
      int s = i * 256 + tid;
      int row = s >> 3, c = (s & 7) ^ (row & 7);
      gl2lds16(&A[(size_t)(m0 + row) * DM + k0 + c * 8], &As[(s & ~63) * 8]);
      gl2lds16(&Bt[(size_t)(n0 + row) * DM + k0 + c * 8], &Bs[(s & ~63) * 8]);
    }
    __syncthreads();
#pragma unroll
    for (int kk = 0; kk < 2; ++kk) {
      bf16x8 af[4], bfr[4];
#pragma unroll
      for (int mt = 0; mt < 4; ++mt) {
        int row = wm + mt * 16 + l15;
        int c = (kk * 4 + quad) ^ (row & 7);
        af[mt] = *(const bf16x8*)&As[row * 64 + c * 8];
      }
#pragma unroll
      for (int nt = 0; nt < 4; ++nt) {
        int row = wn + nt * 16 + l15;
        int c = (kk * 4 + quad) ^ (row & 7);
        bfr[nt] = *(const bf16x8*)&Bs[row * 64 + c * 8];
      }
#pragma unroll
      for (int mt = 0; mt < 4; ++mt)
#pragma unroll
        for (int nt = 0; nt < 4; ++nt)
          acc[mt][nt] = __builtin_amdgcn_mfma_f32_16x16x32_bf16(af[mt], bfr[nt], acc[mt][nt], 0, 0, 0);
    }
    __syncthreads();
  }
}

// z=0 -> Q, z=1 -> K (row-major bf16), z=2 -> V stored TRANSPOSED into Vt (b,h,d,s)
__global__ __launch_bounds__(256) void qkv_gemm(const u16* __restrict__ X, const u16* __restrict__ Wt,
                                                u16* __restrict__ Qo, u16* __restrict__ Ko,
                                                u16* __restrict__ Vto) {
  __shared__ u16 As[128 * 64];
  __shared__ u16 Bs[128 * 64];
  const u16* Bt = Wt + (size_t)blockIdx.z * DM * DM;
  int n0 = blockIdx.x * 128, m0 = blockIdx.y * 128;
  f32x4 acc[4][4] = {};
  gemm_core(X, Bt, m0, n0, As, Bs, acc);
  int lane = threadIdx.x & 63, wave = threadIdx.x >> 6;
  int l15 = lane & 15, quad = lane >> 4;
  int wm = (wave >> 1) * 64, wn = (wave & 1) * 64;
  if (blockIdx.z == 2) {
    int h = n0 >> 7;
#pragma unroll
    for (int mt = 0; mt < 4; ++mt)
#pragma unroll
      for (int nt = 0; nt < 4; ++nt) {
        int tok = m0 + wm + mt * 16 + quad * 4;
        int d = wn + nt * 16 + l15;
        int b = tok >> 11, sx = tok & (SEQ - 1);
        u16* dp = &Vto[((size_t)(b * NH + h) * HD + d) * SEQ + sx];
        *(u32*)&dp[0] = pack2(acc[mt][nt][0], acc[mt][nt][1]);
        *(u32*)&dp[2] = pack2(acc[mt][nt][2], acc[mt][nt][3]);
      }
  } else {
    u16* C = blockIdx.z == 0 ? Qo : Ko;
#pragma unroll
    for (int mt = 0; mt < 4; ++mt)
#pragma unroll
      for (int nt = 0; nt < 4; ++nt)
#pragma unroll
        for (int r = 0; r < 4; ++r)
          C[(size_t)(m0 + wm + mt * 16 + quad * 4 + r) * DM + n0 + wn + nt * 16 + l15]
              = f2bf(acc[mt][nt][r]);
  }
}

__global__ __launch_bounds__(256) void proj_gemm(const u16* __restrict__ A, const u16* __restrict__ Wt,
                                                 float* __restrict__ C) {
  __shared__ u16 As[128 * 64];
  __shared__ u16 Bs[128 * 64];
  int n0 = blockIdx.x * 128, m0 = blockIdx.y * 128;
  f32x4 acc[4][4] = {};
  gemm_core(A, Wt, m0, n0, As, Bs, acc);
  int lane = threadIdx.x & 63, wave = threadIdx.x >> 6;
  int l15 = lane & 15, quad = lane >> 4;
  int wm = (wave >> 1) * 64, wn = (wave & 1) * 64;
#pragma unroll
  for (int mt = 0; mt < 4; ++mt)
#pragma unroll
    for (int nt = 0; nt < 4; ++nt)
#pragma unroll
      for (int r = 0; r < 4; ++r)
        C[(size_t)(m0 + wm + mt * 16 + quad * 4 + r) * DM + n0 + wn + nt * 16 + l15] = acc[mt][nt][r];
}

// ---------------- RoPE in-place on Q (y=0) and K (y=1) ----------------
__global__ __launch_bounds__(256) void rope_k(u16* __restrict__ Q, u16* __restrict__ K,
                                              const int* __restrict__ pos) {
  uint32_t idx = blockIdx.x * 256 + threadIdx.x;
  int i = idx & 63;
  int h = (idx >> 6) & 15;
  int s = (idx >> 10) & 2047;
  int b = idx >> 21;
  u16* P = (blockIdx.y == 0) ? Q : K;
  int p = pos[b * SEQ + s];
  float inv = exp2f((float)i * -0.20762051f);   // 10000^(-i/64)
  float ang = (float)p * inv;
  float sn, cs;
  sincosf(ang, &sn, &cs);
  size_t base = ((size_t)(b * SEQ + s)) * DM + h * HD;
  float x1 = bf2f(P[base + i]), x2 = bf2f(P[base + 64 + i]);
  P[base + i] = f2bf(x1 * cs - x2 * sn);
  P[base + 64 + i] = f2bf(x2 * cs + x1 * sn);
}

// ---------------- Flash attention: static dbuf, index masking, 32 q/wave ----------------
__global__ __launch_bounds__(256) void attn_k(const u16* __restrict__ Q, const u16* __restrict__ K,
                                              const u16* __restrict__ Vt, const int* __restrict__ pos,
                                              u16* __restrict__ AO) {
  __shared__ u16 Ks0[64 * 128], Ks1[64 * 128];   // swizzled: slot = row*16 + (c ^ (row&15))
  __shared__ u16 Vs0[128 * 64], Vs1[128 * 64];   // swizzled: slot = row*8  + (c ^ (row&7))
  int bx = blockIdx.x, bh = blockIdx.y;
  int b = bh >> 4, h = bh & 15;
  int qt = b ? (15 - bx) : bx;   // complementary pairing for per-CU balance
  int tid = threadIdx.x, lane = tid & 63, wave = tid >> 6;
  int l15 = lane & 15, quad = lane >> 4;
  const int* posb = pos + b * SEQ;
  int qbase = qt * 128 + wave * 16;
  const u16* Kbase = &K[(size_t)(b * SEQ) * DM + h * HD];
  const u16* Vbase = &Vt[(size_t)(b * NH + h) * HD * SEQ];

  // stage tile 0 early (overlaps with searches / qf loads below)
  auto prefetch = [&](int t, u16* KsD, u16* VsD) {
#pragma unroll
    for (int i = 0; i < 4; ++i) {
      int s = i * 256 + tid;
      int rk = s >> 4, ck = (s & 15) ^ (rk & 15);
      gl2lds16(&Kbase[(size_t)(t * 64 + rk) * DM + ck * 8], &KsD[(s & ~63) * 8]);
      int rv = s >> 3, cv = (s & 7) ^ (rv & 7);
      gl2lds16(&Vbase[(size_t)rv * SEQ + t * 64 + cv * 8], &VsD[(s & ~63) * 8]);
    }
  };
  prefetch(0, Ks0, Vs0);

  // Q fragments resident (B-operand layout: n=l15, k=quad*8+j), 2 q-tiles per wave
  bf16x8 qf[2][4];
#pragma unroll
  for (int qi = 0; qi < 2; ++qi)
#pragma unroll
    for (int kk = 0; kk < 4; ++kk)
      qf[qi][kk] = *(const bf16x8*)&Q[(size_t)(b * SEQ + qbase + qi * 64 + l15) * DM
                                      + h * HD + kk * 32 + quad * 8];

  // sorted positions => visible keys for q are a prefix [0, cnt). upper_bound search.
  auto ub = [&](int v) {
    int c = 0;
#pragma unroll
    for (int st = 1024; st; st >>= 1)
      if (posb[c + st - 1] <= v) c += st;
    if (c == 2047 && posb[2047] <= v) c = 2048;
    return c;
  };
  int cnt[2];
  cnt[0] = ub(posb[qbase + l15]);
  cnt[1] = ub(posb[qbase + 64 + l15]);
  int cnt_min = ub(posb[qt * 128]);          // block-uniform (first q has min pos)
  int cnt_max = ub(posb[qt * 128 + 127]);
  int ntile = (cnt_max + 63) >> 6;

  float m_i[2] = {-1.0e30f, -1.0e30f}, l_i[2] = {0.0f, 0.0f};
  f32x4 oacc[2][8] = {};   // O^T per q-tile: row d = dt*16+quad*4+r, col q = l15

  int base0 = l15 + ((quad & 1) << 5);
  bool hi_sel = (quad >> 1) != 0;

  auto compute = [&](int j0, const u16* KsS, const u16* VsS) {
    // S^T[key][q]: sacc[qi][kt] elem r -> key = j0 + kt*16 + quad*4 + r, q = l15
    f32x4 sacc[2][4] = {};
#pragma unroll
    for (int kk = 0; kk < 4; ++kk) {
      bf16x8 kf[4];
#pragma unroll
      for (int kt = 0; kt < 4; ++kt) {
        int row = kt * 16 + l15;
        int c = (kk * 4 + quad) ^ (row & 15);
        kf[kt] = *(const bf16x8*)&KsS[row * 128 + c * 8];
      }
#pragma unroll
      for (int qi = 0; qi < 2; ++qi)
#pragma unroll
        for (int kt = 0; kt < 4; ++kt)
          sacc[qi][kt] = __builtin_amdgcn_mfma_f32_16x16x32_bf16(kf[kt], qf[qi][kk], sacc[qi][kt], 0, 0, 0);
    }

    bool need_mask = (j0 + 64 > cnt_min);   // block-uniform branch
    u32 pb[2][4][2];
#pragma unroll
    for (int qi = 0; qi < 2; ++qi) {
      if (need_mask) {
        int rel = cnt[qi] - j0;
#pragma unroll
        for (int kt = 0; kt < 4; ++kt)
#pragma unroll
          for (int r = 0; r < 4; ++r)
            if (kt * 16 + quad * 4 + r >= rel) sacc[qi][kt][r] = -1.0e30f;
      }
      float mx = fmaxf(fmaxf(sacc[qi][0][0], sacc[qi][0][1]), fmaxf(sacc[qi][0][2], sacc[qi][0][3]));
#pragma unroll
      for (int kt = 1; kt < 4; ++kt) {
        mx = fmaxf(mx, fmaxf(fmaxf(sacc[qi][kt][0], sacc[qi][kt][1]),
                             fmaxf(sacc[qi][kt][2], sacc[qi][kt][3])));
      }
      mx = fmaxf(mx, __shfl_xor(mx, 16));
      mx = fmaxf(mx, __shfl_xor(mx, 32));
      float mold = m_i[qi];
      float mn = fmaxf(mold, mx);
      if (__any(mn > mold)) {                 // skip rescale when max unchanged wave-wide
        float al = exp2f((mold - mn) * K2LOG);
        l_i[qi] *= al;
#pragma unroll
        for (int dt = 0; dt < 8; ++dt) oacc[qi][dt] *= al;
        m_i[qi] = mn;
      }
      float nc = -m_i[qi] * K2LOG;
      float rs = 0.0f;
#pragma unroll
      for (int kt = 0; kt < 4; ++kt) {
        float p0 = exp2f(fmaf(sacc[qi][kt][0], K2LOG, nc));
        float p1 = exp2f(fmaf(sacc[qi][kt][1], K2LOG, nc));
        float p2 = exp2f(fmaf(sacc[qi][kt][2], K2LOG, nc));
        float p3 = exp2f(fmaf(sacc[qi][kt][3], K2LOG, nc));
        rs += (p0 + p1) + (p2 + p3);
        pb[qi][kt][0] = pack2_trunc(p0, p1);
        pb[qi][kt][1] = pack2_trunc(p2, p3);
      }
      rs += __shfl_xor(rs, 16);
      rs += __shfl_xor(rs, 32);
      l_i[qi] += rs;
    }

    // O^T += V^T . P^T ; vf shared across both q-tiles; P^T B-frag built via bpermute
#pragma unroll
    for (int kk = 0; kk < 2; ++kk) {
      bf16x8 vf[8];
#pragma unroll
      for (int dt = 0; dt < 8; ++dt) {
        int row = dt * 16 + l15;
        int c = (kk * 4 + quad) ^ (row & 7);
        vf[dt] = *(const bf16x8*)&VsS[row * 64 + c * 8];
      }
#pragma unroll
      for (int qi = 0; qi < 2; ++qi) {
        u32 w[4];
#pragma unroll
        for (int wd = 0; wd < 4; ++wd) {
          int src = base0 + ((wd >> 1) << 4);
          u32 va = __shfl(pb[qi][kk * 2 + 0][wd & 1], src);
          u32 vb = __shfl(pb[qi][kk * 2 + 1][wd & 1], src);
          w[wd] = hi_sel ? vb : va;
        }
        union { bf16x8 v; u32 u[4]; } pt;
        pt.u[0] = w[0]; pt.u[1] = w[1]; pt.u[2] = w[2]; pt.u[3] = w[3];
#pragma unroll
        for (int dt = 0; dt < 8; ++dt)
          oacc[qi][dt] = __builtin_amdgcn_mfma_f32_16x16x32_bf16(vf[dt], pt.v, oacc[qi][dt], 0, 0, 0);
      }
    }
  };

  // main loop, unrolled x2 so buffers are compile-time (static alias disambiguation)
  for (int j = 0; j < ntile; j += 2) {
    __syncthreads();                                  // publishes buf0 tile j
    if (j + 1 < ntile) prefetch(j + 1, Ks1, Vs1);     // DMA into buf1 overlaps compute
    compute(j * 64, Ks0, Vs0);
    if (j + 1 >= ntile) break;
    __syncthreads();                                  // publishes buf1 tile j+1
    if (j + 2 < ntile) prefetch(j + 2, Ks0, Vs0);
    compute((j + 1) * 64, Ks1, Vs1);
  }

  // epilogue
#pragma unroll
  for (int qi = 0; qi < 2; ++qi) {
    float inv = 1.0f / l_i[qi];
    u16* aop = &AO[(size_t)(b * SEQ + qbase + qi * 64 + l15) * DM + h * HD];
#pragma unroll
    for (int dt = 0; dt < 8; ++dt) {
      int col = dt * 16 + quad * 4;
      *(u32*)&aop[col]     = pack2(oacc[qi][dt][0] * inv, oacc[qi][dt][1] * inv);
      *(u32*)&aop[col + 2] = pack2(oacc[qi][dt][2] * inv, oacc[qi][dt][3] * inv);
    }
  }
}

extern "C" void kernel_launch(void* const* d_in, const int* in_sizes, int n_in,
                              void* d_out, int out_size, void* d_ws, size_t ws_size,
                              hipStream_t stream) {
  const float* x  = (const float*)d_in[0];
  const float* Wq = (const float*)d_in[1];
  const float* Wk = (const float*)d_in[2];
  const float* Wv = (const float*)d_in[3];
  const float* Wo = (const float*)d_in[4];
  const int*  pos = (const int*)d_in[5];
  float* out = (float*)d_out;

  u16* ws  = (u16*)d_ws;
  u16* xb  = ws;
  u16* wt  = xb  + (size_t)4096 * 2048;
  u16* qb  = wt  + (size_t)4 * 2048 * 2048;
  u16* kb  = qb  + (size_t)4096 * 2048;
  u16* vtb = kb  + (size_t)4096 * 2048;
  u16* aob = vtb + (size_t)4096 * 2048;

  cvt_x<<<8192, 256, 0, stream>>>(x, xb);
  wtrans<<<dim3(64, 64, 4), dim3(32, 8), 0, stream>>>(Wq, Wk, Wv, Wo, wt);
  qkv_gemm<<<dim3(16, 32, 3), 256, 0, stream>>>(xb, wt, qb, kb, vtb);
  rope_k<<<dim3(16384, 2), 256, 0, stream>>>(qb, kb, pos);
  attn_k<<<dim3(16, 32), 256, 0, stream>>>(qb, kb, vtb, pos, aob);
  proj_gemm<<<dim3(16, 32), 256, 0, stream>>>(aob, wt + (size_t)3 * 2048 * 2048, out);
}

// Round 6
// 453.041 us; speedup vs baseline: 1.3741x; 1.0138x over previous
//
#include <hip/hip_runtime.h>
#include <stdint.h>

// R6: attn_k rewritten as barrier-free L2-streaming flash attention:
//   - K/V fragments loaded DIRECTLY from global in MFMA A-frag layout (16B/lane;
//     quads of each l15 cover full 64B sectors -> fully-used L2 requests).
//   - No LDS staging, no DMA, no __syncthreads. Each wave = independent 32-q job.
//   - Complementary stripe map (t<32 ? 2t : 127-2t) -> co-resident work ~constant.
//   - P^T B-frags still built in-register via shuffles (R5, verified).
//   rope_k: sincosf (libm big-arg reduction) -> exact-FMA revolution fraction + __sinf.
// GEMMs / wtrans / cvt unchanged (m97 structure).

typedef unsigned short u16;
typedef unsigned int u32;
typedef __attribute__((ext_vector_type(8))) short bf16x8;
typedef __attribute__((ext_vector_type(4))) float f32x4;

#define SEQ 2048
#define DM 2048
#define NH 16
#define HD 128
#define SM_SCALE 0.08838834764831845f
#define K2LOG 0.12751743f   // SM_SCALE * log2(e)

__device__ __forceinline__ u16 f2bf(float f) {
  union { float f; uint32_t u; } v; v.f = f;
  uint32_t u = v.u + 0x7fffu + ((v.u >> 16) & 1u);   // RNE
  return (u16)(u >> 16);
}
__device__ __forceinline__ float bf2f(u16 h) {
  union { uint32_t u; float f; } v; v.u = ((uint32_t)h) << 16; return v.f;
}
__device__ __forceinline__ u32 pack2(float a, float b) {
  return (u32)f2bf(a) | ((u32)f2bf(b) << 16);
}
__device__ __forceinline__ u32 pack2_trunc(float a, float b) {   // RTZ: P in [0,1]
  union { float f; u32 u; } x, y; x.f = a; y.f = b;
  return (x.u >> 16) | (y.u & 0xFFFF0000u);
}

// async global->LDS, 16B per lane (GEMMs only now)
__device__ __forceinline__ void gl2lds16(const void* g, void* l) {
  __builtin_amdgcn_global_load_lds(
      (const __attribute__((address_space(1))) uint32_t*)g,
      (__attribute__((address_space(3))) uint32_t*)l, 16, 0, 0);
}

// ---------------- elementwise fp32 -> bf16 of x ----------------
__global__ __launch_bounds__(256) void cvt_x(const float* __restrict__ x, u16* __restrict__ xb) {
  int i = blockIdx.x * 256 + threadIdx.x;
  float4 v = ((const float4*)x)[i];
  uint2 r;
  r.x = pack2(v.x, v.y);
  r.y = pack2(v.z, v.w);
  ((uint2*)xb)[i] = r;
}

// ---------------- W (K,N) fp32 -> Wt (N,K) bf16, tiled transpose ----------------
__global__ __launch_bounds__(256) void wtrans(const float* __restrict__ w0, const float* __restrict__ w1,
                                              const float* __restrict__ w2, const float* __restrict__ w3,
                                              u16* __restrict__ dst) {
  const float* W = blockIdx.z == 0 ? w0 : blockIdx.z == 1 ? w1 : blockIdx.z == 2 ? w2 : w3;
  u16* D = dst + (size_t)blockIdx.z * DM * DM;
  int k0 = blockIdx.x * 32, n0 = blockIdx.y * 32;
  __shared__ u16 t[32][33];
  int tx = threadIdx.x, ty = threadIdx.y;   // (32,8)
#pragma unroll
  for (int i = 0; i < 32; i += 8)
    t[ty + i][tx] = f2bf(W[(size_t)(k0 + ty + i) * DM + n0 + tx]);
  __syncthreads();
#pragma unroll
  for (int i = 0; i < 32; i += 8)
    D[(size_t)(n0 + ty + i) * DM + k0 + tx] = t[tx][ty + i];
}

// ---------------- 128x128 (BK=64) bf16 MFMA GEMM core, global_load_lds staging ----------------
__device__ __forceinline__ void gemm_core(const u16* __restrict__ A, const u16* __restrict__ Bt,
                                          int m0, int n0, u16* As, u16* Bs, f32x4 acc[4][4]) {
  int tid = threadIdx.x, lane = tid & 63;
  int l15 = lane & 15, quad = lane >> 4;
  int wave = tid >> 6;
  int wm = (wave >> 1) * 64, wn = (wave & 1) * 64;
  for (int k0 = 0; k0 < DM; k0 += 64) {
#pragma unroll
    for (int i = 0; i < 4; ++i) {
      int s = i * 256 + tid;
      int row = s >> 3, c = (s & 7) ^ (row & 7);
      gl2lds16(&A[(size_t)(m0 + row) * DM + k0 + c * 8], &As[(s & ~63) * 8]);
      gl2lds16(&Bt[(size_t)(n0 + row) * DM + k0 + c * 8], &Bs[(s & ~63) * 8]);
    }
    __syncthreads();
#pragma unroll
    for (int kk = 0; kk < 2; ++kk) {
      bf16x8 af[4], bfr[4];
#pragma unroll
      for (int mt = 0; mt < 4; ++mt) {
        int row = wm + mt * 16 + l15;
        int c = (kk * 4 + quad) ^ (row & 7);
        af[mt] = *(const bf16x8*)&As[row * 64 + c * 8];
      }
#pragma unroll
      for (int nt = 0; nt < 4; ++nt) {
        int row = wn + nt * 16 + l15;
        int c = (kk * 4 + quad) ^ (row & 7);
        bfr[nt] = *(const bf16x8*)&Bs[row * 64 + c * 8];
      }
#pragma unroll
      for (int mt = 0; mt < 4; ++mt)
#pragma unroll
        for (int nt = 0; nt < 4; ++nt)
          acc[mt][nt] = __builtin_amdgcn_mfma_f32_16x16x32_bf16(af[mt], bfr[nt], acc[mt][nt], 0, 0, 0);
    }
    __syncthreads();
  }
}

// z=0 -> Q, z=1 -> K (row-major bf16), z=2 -> V stored TRANSPOSED into Vt (b,h,d,s)
__global__ __launch_bounds__(256) void qkv_gemm(const u16* __restrict__ X, const u16* __restrict__ Wt,
                                                u16* __restrict__ Qo, u16* __restrict__ Ko,
                                                u16* __restrict__ Vto) {
  __shared__ u16 As[128 * 64];
  __shared__ u16 Bs[128 * 64];
  const u16* Bt = Wt + (size_t)blockIdx.z * DM * DM;
  int n0 = blockIdx.x * 128, m0 = blockIdx.y * 128;
  f32x4 acc[4][4] = {};
  gemm_core(X, Bt, m0, n0, As, Bs, acc);
  int lane = threadIdx.x & 63, wave = threadIdx.x >> 6;
  int l15 = lane & 15, quad = lane >> 4;
  int wm = (wave >> 1) * 64, wn = (wave & 1) * 64;
  if (blockIdx.z == 2) {
    int h = n0 >> 7;
#pragma unroll
    for (int mt = 0; mt < 4; ++mt)
#pragma unroll
      for (int nt = 0; nt < 4; ++nt) {
        int tok = m0 + wm + mt * 16 + quad * 4;
        int d = wn + nt * 16 + l15;
        int b = tok >> 11, sx = tok & (SEQ - 1);
        u16* dp = &Vto[((size_t)(b * NH + h) * HD + d) * SEQ + sx];
        *(u32*)&dp[0] = pack2(acc[mt][nt][0], acc[mt][nt][1]);
        *(u32*)&dp[2] = pack2(acc[mt][nt][2], acc[mt][nt][3]);
      }
  } else {
    u16* C = blockIdx.z == 0 ? Qo : Ko;
#pragma unroll
    for (int mt = 0; mt < 4; ++mt)
#pragma unroll
      for (int nt = 0; nt < 4; ++nt)
#pragma unroll
        for (int r = 0; r < 4; ++r)
          C[(size_t)(m0 + wm + mt * 16 + quad * 4 + r) * DM + n0 + wn + nt * 16 + l15]
              = f2bf(acc[mt][nt][r]);
  }
}

__global__ __launch_bounds__(256) void proj_gemm(const u16* __restrict__ A, const u16* __restrict__ Wt,
                                                 float* __restrict__ C) {
  __shared__ u16 As[128 * 64];
  __shared__ u16 Bs[128 * 64];
  int n0 = blockIdx.x * 128, m0 = blockIdx.y * 128;
  f32x4 acc[4][4] = {};
  gemm_core(A, Wt, m0, n0, As, Bs, acc);
  int lane = threadIdx.x & 63, wave = threadIdx.x >> 6;
  int l15 = lane & 15, quad = lane >> 4;
  int wm = (wave >> 1) * 64, wn = (wave & 1) * 64;
#pragma unroll
  for (int mt = 0; mt < 4; ++mt)
#pragma unroll
    for (int nt = 0; nt < 4; ++nt)
#pragma unroll
      for (int r = 0; r < 4; ++r)
        C[(size_t)(m0 + wm + mt * 16 + quad * 4 + r) * DM + n0 + wn + nt * 16 + l15] = acc[mt][nt][r];
}

// ---------------- RoPE in-place on Q (y=0) and K (y=1), fast sincos ----------------
__global__ __launch_bounds__(256) void rope_k(u16* __restrict__ Q, u16* __restrict__ K,
                                              const int* __restrict__ pos) {
  uint32_t idx = blockIdx.x * 256 + threadIdx.x;
  int i = idx & 63;
  int h = (idx >> 6) & 15;
  int s = (idx >> 10) & 2047;
  int b = idx >> 21;
  u16* P = (blockIdx.y == 0) ? Q : K;
  int p = pos[b * SEQ + s];
  // inv_rev = 10000^(-i/64) / (2*pi) = exp2(-i*log2(1e4)/64 - log2(2pi))
  float inv_rev = exp2f(fmaf((float)i, -0.20762051f, -2.6514961f));
  float pf = (float)p;
  float hi = pf * inv_rev;
  float err = fmaf(pf, inv_rev, -hi);          // exact FMA residual
  float r = (hi - truncf(hi)) + err;           // frac(p*inv_rev), ~2^-24 rev accuracy
  float ang = r * 6.2831853f;                  // [0, 2pi): no big-arg reduction needed
  float sn = __sinf(ang), cs = __cosf(ang);
  size_t base = ((size_t)(b * SEQ + s)) * DM + h * HD;
  float x1 = bf2f(P[base + i]), x2 = bf2f(P[base + 64 + i]);
  P[base + i] = f2bf(x1 * cs - x2 * sn);
  P[base + 64 + i] = f2bf(x2 * cs + x1 * sn);
}

// ---------------- Flash attention: barrier-free, L2-streaming, 32 q per wave ----------------
// Wave-job J: bh = J&31, t = J>>5, stripe = t<32 ? 2t : 127-2t (complementary balance).
// qi in {0,1}: q = stripe*32 + qi*16 + l15. K/V frags loaded directly from global.
__global__ __launch_bounds__(256, 2) void attn_k(const u16* __restrict__ Q, const u16* __restrict__ K,
                                                 const u16* __restrict__ Vt, const int* __restrict__ pos,
                                                 u16* __restrict__ AO) {
  int tid = threadIdx.x, lane = tid & 63, wave = tid >> 6;
  int J = blockIdx.x * 4 + wave;
  int bh = J & 31;
  int t = J >> 5;
  int stripe = (t < 32) ? (2 * t) : (127 - 2 * t);
  int b = bh >> 4, h = bh & 15;
  int l15 = lane & 15, quad = lane >> 4;
  const int* posb = pos + b * SEQ;
  int qbase = stripe * 32;
  const u16* Kbase = &K[(size_t)(b * SEQ) * DM + h * HD];
  const u16* Vbase = &Vt[(size_t)(b * NH + h) * HD * SEQ];

  // Q fragments resident (B-operand layout: n=l15, k=quad*8+j)
  bf16x8 qf[2][4];
#pragma unroll
  for (int qi = 0; qi < 2; ++qi)
#pragma unroll
    for (int kk = 0; kk < 4; ++kk)
      qf[qi][kk] = *(const bf16x8*)&Q[(size_t)(b * SEQ + qbase + qi * 16 + l15) * DM
                                      + h * HD + kk * 32 + quad * 8];

  // sorted positions => visible keys are a prefix [0, cnt)
  auto ub = [&](int v) {
    int c = 0;
#pragma unroll
    for (int st = 1024; st; st >>= 1)
      if (posb[c + st - 1] <= v) c += st;
    if (c == 2047 && posb[2047] <= v) c = 2048;
    return c;
  };
  int cnt[2];
  cnt[0] = ub(posb[qbase + l15]);
  cnt[1] = ub(posb[qbase + 16 + l15]);
  int cnt_min = ub(posb[qbase]);            // wave-uniform
  int cnt_max = ub(posb[qbase + 31]);
  int ntile = (cnt_max + 63) >> 6;

  float m_i[2] = {-1.0e30f, -1.0e30f}, l_i[2] = {0.0f, 0.0f};
  f32x4 oacc[2][8] = {};   // O^T per qi: row d = dt*16+quad*4+r, col q = l15

  int base0 = l15 + ((quad & 1) << 5);
  bool hi_sel = (quad >> 1) != 0;

  for (int j = 0; j < ntile; ++j) {
    int j0 = j * 64;
    // K fragments direct from global: A-frag m=key=kt*16+l15, k=d=kk*32+quad*8..
    bf16x8 kf[4][4];
#pragma unroll
    for (int kk = 0; kk < 4; ++kk)
#pragma unroll
      for (int kt = 0; kt < 4; ++kt)
        kf[kk][kt] = *(const bf16x8*)&Kbase[(size_t)(j0 + kt * 16 + l15) * DM + kk * 32 + quad * 8];

    // S^T[key][q]: sacc[qi][kt] elem r -> key = j0 + kt*16 + quad*4 + r, q = l15
    f32x4 sacc[2][4] = {};
#pragma unroll
    for (int kk = 0; kk < 4; ++kk)
#pragma unroll
      for (int qi = 0; qi < 2; ++qi)
#pragma unroll
        for (int kt = 0; kt < 4; ++kt)
          sacc[qi][kt] = __builtin_amdgcn_mfma_f32_16x16x32_bf16(kf[kk][kt], qf[qi][kk], sacc[qi][kt], 0, 0, 0);

    // V fragments issued BEFORE softmax so their latency hides under the VALU block.
    // A-frag m=d=dt*16+l15, k=key=j0+kk2*32+quad*8..
    bf16x8 vf[2][8];
#pragma unroll
    for (int kk2 = 0; kk2 < 2; ++kk2)
#pragma unroll
      for (int dt = 0; dt < 8; ++dt)
        vf[kk2][dt] = *(const bf16x8*)&Vbase[(size_t)(dt * 16 + l15) * SEQ + j0 + kk2 * 32 + quad * 8];

    bool need_mask = (j0 + 64 > cnt_min);   // wave-uniform branch
    u32 pb[2][4][2];
#pragma unroll
    for (int qi = 0; qi < 2; ++qi) {
      if (need_mask) {
        int rel = cnt[qi] - j0;
#pragma unroll
        for (int kt = 0; kt < 4; ++kt)
#pragma unroll
          for (int r = 0; r < 4; ++r)
            if (kt * 16 + quad * 4 + r >= rel) sacc[qi][kt][r] = -1.0e30f;
      }
      float mx = fmaxf(fmaxf(sacc[qi][0][0], sacc[qi][0][1]), fmaxf(sacc[qi][0][2], sacc[qi][0][3]));
#pragma unroll
      for (int kt = 1; kt < 4; ++kt)
        mx = fmaxf(mx, fmaxf(fmaxf(sacc[qi][kt][0], sacc[qi][kt][1]),
                             fmaxf(sacc[qi][kt][2], sacc[qi][kt][3])));
      mx = fmaxf(mx, __shfl_xor(mx, 16));
      mx = fmaxf(mx, __shfl_xor(mx, 32));
      float mold = m_i[qi];
      float mn = fmaxf(mold, mx);
      if (__any(mn > mold)) {
        float al = exp2f((mold - mn) * K2LOG);
        l_i[qi] *= al;
#pragma unroll
        for (int dt = 0; dt < 8; ++dt) oacc[qi][dt] *= al;
        m_i[qi] = mn;
      }
      float nc = -m_i[qi] * K2LOG;
      float rs = 0.0f;
#pragma unroll
      for (int kt = 0; kt < 4; ++kt) {
        float p0 = exp2f(fmaf(sacc[qi][kt][0], K2LOG, nc));
        float p1 = exp2f(fmaf(sacc[qi][kt][1], K2LOG, nc));
        float p2 = exp2f(fmaf(sacc[qi][kt][2], K2LOG, nc));
        float p3 = exp2f(fmaf(sacc[qi][kt][3], K2LOG, nc));
        rs += (p0 + p1) + (p2 + p3);
        pb[qi][kt][0] = pack2_trunc(p0, p1);
        pb[qi][kt][1] = pack2_trunc(p2, p3);
      }
      rs += __shfl_xor(rs, 16);
      rs += __shfl_xor(rs, 32);
      l_i[qi] += rs;
    }

    // O^T += V^T . P^T ; P^T B-frag built via shuffles (verified R5 mapping)
#pragma unroll
    for (int kk2 = 0; kk2 < 2; ++kk2) {
#pragma unroll
      for (int qi = 0; qi < 2; ++qi) {
        u32 w[4];
#pragma unroll
        for (int wd = 0; wd < 4; ++wd) {
          int src = base0 + ((wd >> 1) << 4);
          u32 va = __shfl(pb[qi][kk2 * 2 + 0][wd & 1], src);
          u32 vb = __shfl(pb[qi][kk2 * 2 + 1][wd & 1], src);
          w[wd] = hi_sel ? vb : va;
        }
        union { bf16x8 v; u32 u[4]; } pt;
        pt.u[0] = w[0]; pt.u[1] = w[1]; pt.u[2] = w[2]; pt.u[3] = w[3];
#pragma unroll
        for (int dt = 0; dt < 8; ++dt)
          oacc[qi][dt] = __builtin_amdgcn_mfma_f32_16x16x32_bf16(vf[kk2][dt], pt.v, oacc[qi][dt], 0, 0, 0);
      }
    }
  }

  // epilogue: O[q][d] = O^T / l
#pragma unroll
  for (int qi = 0; qi < 2; ++qi) {
    float inv = 1.0f / l_i[qi];
    u16* aop = &AO[(size_t)(b * SEQ + qbase + qi * 16 + l15) * DM + h * HD];
#pragma unroll
    for (int dt = 0; dt < 8; ++dt) {
      int col = dt * 16 + quad * 4;
      *(u32*)&aop[col]     = pack2(oacc[qi][dt][0] * inv, oacc[qi][dt][1] * inv);
      *(u32*)&aop[col + 2] = pack2(oacc[qi][dt][2] * inv, oacc[qi][dt][3] * inv);
    }
  }
}

extern "C" void kernel_launch(void* const* d_in, const int* in_sizes, int n_in,
                              void* d_out, int out_size, void* d_ws, size_t ws_size,
                              hipStream_t stream) {
  const float* x  = (const float*)d_in[0];
  const float* Wq = (const float*)d_in[1];
  const float* Wk = (const float*)d_in[2];
  const float* Wv = (const float*)d_in[3];
  const float* Wo = (const float*)d_in[4];
  const int*  pos = (const int*)d_in[5];
  float* out = (float*)d_out;

  u16* ws  = (u16*)d_ws;
  u16* xb  = ws;
  u16* wt  = xb  + (size_t)4096 * 2048;
  u16* qb  = wt  + (size_t)4 * 2048 * 2048;
  u16* kb  = qb  + (size_t)4096 * 2048;
  u16* vtb = kb  + (size_t)4096 * 2048;
  u16* aob = vtb + (size_t)4096 * 2048;

  cvt_x<<<8192, 256, 0, stream>>>(x, xb);
  wtrans<<<dim3(64, 64, 4), dim3(32, 8), 0, stream>>>(Wq, Wk, Wv, Wo, wt);
  qkv_gemm<<<dim3(16, 32, 3), 256, 0, stream>>>(xb, wt, qb, kb, vtb);
  rope_k<<<dim3(16384, 2), 256, 0, stream>>>(qb, kb, pos);
  attn_k<<<dim3(512), 256, 0, stream>>>(qb, kb, vtb, pos, aob);
  proj_gemm<<<dim3(16, 32), 256, 0, stream>>>(aob, wt + (size_t)3 * 2048 * 2048, out);
}